// Round 9
// baseline (1777.472 us; speedup 1.0000x reference)
//
#include <hip/hip_runtime.h>

// Problem constants (hardcoded from reference)
#define BD   32768               // boards
#define NPG  54                  // nodes per graph
#define NN   (BD * NPG)          // 1,769,472 nodes = 1728 * 1024 exactly
#define NE   (BD * 144)          // 4,718,592 edges
#define DIN  16
#define DH   32
#define GLOBF 16
#define TB   32                  // boards per block in final kernel
#define SRCM 0x1FFFFFu           // 21-bit src mask (NN < 2^21)

// --- new-path constants (CSR message push) ---
#define SRCB 512                 // nodes per src bucket
#define NSB  (NN / SRCB)         // 3456 src buckets
#define DSH  9                   // src_lo bits
#define SLOM 511u
#define NSCB 1728                // scan blocks (NN / 1024)

// --- fallback-path constants (round-8 pipeline) ---
#define RB   256
#define NBK  (NN / RB)           // 6912
#define QBK  (NBK / 4)
#define RB2  1024
#define NBK2 (NN / RB2)
#define STR1 17
#define STR2 5

// ===========================================================================
// NEW PATH: src-bucket sort + per-dst-node CSR message push (write-routed)
// ===========================================================================

// hist over dst NODES (cnt, NN counters) and src BUCKETS (hist_src, NSB)
__global__ __launch_bounds__(256) void k_hist2(const int* __restrict__ ei,
                                               unsigned* __restrict__ cnt,
                                               unsigned* __restrict__ hist_src) {
  unsigned e = blockIdx.x * 256u + threadIdx.x;
  unsigned s = (unsigned)ei[e];
  unsigned d = (unsigned)ei[NE + e];
  atomicAdd(&hist_src[s >> DSH], 1u);
  atomicAdd(&cnt[d], 1u);
}

// scan 3456 src-bucket counts (1 block)
__global__ __launch_bounds__(1024) void k_scan_src(const unsigned* __restrict__ hist,
                                                   unsigned* __restrict__ base,
                                                   unsigned* __restrict__ cursor) {
  __shared__ unsigned s[1024];
  const int tid = threadIdx.x;
  unsigned loc[4]; unsigned run = 0;
#pragma unroll
  for (int j = 0; j < 4; ++j) {
    int idx = tid * 4 + j;
    unsigned v = (idx < NSB) ? hist[idx] : 0u;
    loc[j] = run; run += v;
  }
  s[tid] = run; __syncthreads();
  for (int off = 1; off < 1024; off <<= 1) {
    unsigned t = (tid >= off) ? s[tid - off] : 0u;
    __syncthreads(); s[tid] += t; __syncthreads();
  }
  unsigned cb = tid ? s[tid - 1] : 0u;
#pragma unroll
  for (int j = 0; j < 4; ++j) {
    int idx = tid * 4 + j;
    if (idx < NSB) { unsigned b = cb + loc[j]; base[idx] = b; cursor[idx] = b; }
  }
  if (tid == 1023) base[NSB] = s[1023];                  // = NE
}

// node-level scan, stage A: block-local exclusive scan of 1024 counts
__global__ __launch_bounds__(1024) void k_scanA(const unsigned* __restrict__ counts,
                                                unsigned* __restrict__ nbase,
                                                unsigned* __restrict__ bsum) {
  __shared__ unsigned s[1024];
  const int tid = threadIdx.x;
  const unsigned gid = blockIdx.x * 1024u + tid;
  unsigned c = counts[gid];
  s[tid] = c; __syncthreads();
  for (int off = 1; off < 1024; off <<= 1) {
    unsigned t = (tid >= off) ? s[tid - off] : 0u;
    __syncthreads(); s[tid] += t; __syncthreads();
  }
  nbase[gid] = s[tid] - c;                               // local exclusive
  if (tid == 1023) bsum[blockIdx.x] = s[1023];
}

// stage B: scan 1728 block sums (1 block)
__global__ __launch_bounds__(1024) void k_scanB(const unsigned* __restrict__ bsum,
                                                unsigned* __restrict__ bsumx) {
  __shared__ unsigned s[1024];
  const int tid = threadIdx.x;
  unsigned loc[2]; unsigned run = 0;
#pragma unroll
  for (int j = 0; j < 2; ++j) {
    int idx = tid * 2 + j;
    unsigned v = (idx < NSCB) ? bsum[idx] : 0u;
    loc[j] = run; run += v;
  }
  s[tid] = run; __syncthreads();
  for (int off = 1; off < 1024; off <<= 1) {
    unsigned t = (tid >= off) ? s[tid - off] : 0u;
    __syncthreads(); s[tid] += t; __syncthreads();
  }
  unsigned cb = tid ? s[tid - 1] : 0u;
#pragma unroll
  for (int j = 0; j < 2; ++j) {
    int idx = tid * 2 + j;
    if (idx < NSCB) bsumx[idx] = cb + loc[j];
  }
}

// stage C: add block offsets; init both message cursors
__global__ __launch_bounds__(1024) void k_scanC(unsigned* __restrict__ nbase,
                                                const unsigned* __restrict__ bsumx,
                                                unsigned* __restrict__ cur1,
                                                unsigned* __restrict__ cur2) {
  const unsigned gid = blockIdx.x * 1024u + threadIdx.x;
  unsigned v = nbase[gid] + bsumx[blockIdx.x];
  nbase[gid] = v; cur1[gid] = v; cur2[gid] = v;
  if (blockIdx.x == NSCB - 1 && threadIdx.x == 1023) nbase[NN] = NE;
}

// place edges grouped by src bucket: rec = {src_lo:9 | dst<<9, w}
__global__ __launch_bounds__(256) void k_place_src(const int* __restrict__ ei,
                                                   const float* __restrict__ ea,
                                                   unsigned* __restrict__ cursor,
                                                   uint2* __restrict__ rec) {
  unsigned e = blockIdx.x * 256u + threadIdx.x;
  unsigned s = (unsigned)ei[e];
  unsigned d = (unsigned)ei[NE + e];
  float w = ea[e];
  unsigned pos = atomicAdd(&cursor[s >> DSH], 1u);
  rec[pos] = make_uint2((s & SLOM) | (d << DSH), __float_as_uint(w));
}

// msg1 push: per src bucket (x chunk = 32KB, L1-resident), push w*x[src]
// (64B full line) to CSR slot of dst node (random line WRITE).
__global__ __launch_bounds__(256) void k_msg1(
    const uint2* __restrict__ rec, const unsigned* __restrict__ base_src,
    const float* __restrict__ x, unsigned* __restrict__ cur1,
    float4* __restrict__ msg1) {
  const unsigned bk = blockIdx.x;
  const unsigned r0 = base_src[bk], r1 = base_src[bk + 1];
  const unsigned sbase = bk * SRCB;
  for (unsigned i = r0 + threadIdx.x; i < r1; i += 256u) {
    uint2 rv = rec[i];
    unsigned src = sbase + (rv.x & SLOM);
    unsigned dst = rv.x >> DSH;
    float w = __uint_as_float(rv.y);
    const float4* xp = reinterpret_cast<const float4*>(x + (size_t)src * 16);
    float4 v0 = xp[0], v1 = xp[1], v2 = xp[2], v3 = xp[3];
    unsigned slot = atomicAdd(&cur1[dst], 1u);
    float4* mp = msg1 + (size_t)slot * 4;
    v0.x *= w; v0.y *= w; v0.z *= w; v0.w *= w;
    v1.x *= w; v1.y *= w; v1.z *= w; v1.w *= w;
    v2.x *= w; v2.y *= w; v2.z *= w; v2.w *= w;
    v3.x *= w; v3.y *= w; v3.z *= w; v3.w *= w;
    mp[0] = v0; mp[1] = v1; mp[2] = v2; mp[3] = v3;
  }
}

// conv1 aggregate + fused transform: node n sums its contiguous msg1 range,
// then h1 = relu(aggr@W1_rel + x@W1_root + b1), z2 = h1@W2_rel, r2 = h1@W2_root+b2
__global__ __launch_bounds__(256) void k_conv1agg(
    const float4* __restrict__ msg1, const unsigned* __restrict__ nbase,
    const float* __restrict__ x,
    const float* __restrict__ W1_rel, const float* __restrict__ b1,
    const float* __restrict__ W1_root,
    const float* __restrict__ W2_rel, const float* __restrict__ b2,
    const float* __restrict__ W2_root,
    float* __restrict__ z2, float* __restrict__ r2) {
  const size_t n = (size_t)blockIdx.x * 256 + threadIdx.x;
  const unsigned d0 = nbase[n], d1 = nbase[n + 1];
  float a[16];
#pragma unroll
  for (int i = 0; i < 16; ++i) a[i] = 0.f;
  for (unsigned j = d0; j < d1; ++j) {
    const float4* mp = msg1 + (size_t)j * 4;
    float4 m0 = mp[0], m1 = mp[1], m2 = mp[2], m3 = mp[3];
    a[0]  += m0.x; a[1]  += m0.y; a[2]  += m0.z; a[3]  += m0.w;
    a[4]  += m1.x; a[5]  += m1.y; a[6]  += m1.z; a[7]  += m1.w;
    a[8]  += m2.x; a[9]  += m2.y; a[10] += m2.z; a[11] += m2.w;
    a[12] += m3.x; a[13] += m3.y; a[14] += m3.z; a[15] += m3.w;
  }
  float xv[16];
  {
    const float4* xp = reinterpret_cast<const float4*>(x + n * 16);
#pragma unroll
    for (int q = 0; q < 4; ++q) {
      float4 t2 = xp[q];
      xv[4*q+0] = t2.x; xv[4*q+1] = t2.y; xv[4*q+2] = t2.z; xv[4*q+3] = t2.w;
    }
  }
  float h[DH];
#pragma unroll
  for (int j = 0; j < DH; ++j) h[j] = b1[j];
#pragma unroll
  for (int i = 0; i < DIN; ++i) {
    float ai = a[i], xi = xv[i];
#pragma unroll
    for (int j = 0; j < DH; ++j)
      h[j] = fmaf(ai, W1_rel[i * DH + j], fmaf(xi, W1_root[i * DH + j], h[j]));
  }
#pragma unroll
  for (int j = 0; j < DH; ++j) h[j] = fmaxf(h[j], 0.f);
  float z[4] = {0.f, 0.f, 0.f, 0.f};
  float r[4] = {b2[0], b2[1], b2[2], b2[3]};
#pragma unroll
  for (int j = 0; j < DH; ++j) {
    float hj = h[j];
#pragma unroll
    for (int k = 0; k < 4; ++k) {
      z[k] = fmaf(hj, W2_rel[j * 4 + k], z[k]);
      r[k] = fmaf(hj, W2_root[j * 4 + k], r[k]);
    }
  }
  *reinterpret_cast<float4*>(z2 + n * 4) = make_float4(z[0], z[1], z[2], z[3]);
  *reinterpret_cast<float4*>(r2 + n * 4) = make_float4(r[0], r[1], r[2], r[3]);
}

// msg2 push: per src bucket (z2 chunk = 8KB), push w*z2[src] (16B) to CSR slot
__global__ __launch_bounds__(256) void k_msg2(
    const uint2* __restrict__ rec, const unsigned* __restrict__ base_src,
    const float* __restrict__ z2, unsigned* __restrict__ cur2,
    float4* __restrict__ msg2) {
  const unsigned bk = blockIdx.x;
  const unsigned r0 = base_src[bk], r1 = base_src[bk + 1];
  const unsigned sbase = bk * SRCB;
  for (unsigned i = r0 + threadIdx.x; i < r1; i += 256u) {
    uint2 rv = rec[i];
    unsigned src = sbase + (rv.x & SLOM);
    unsigned dst = rv.x >> DSH;
    float w = __uint_as_float(rv.y);
    float4 z = *reinterpret_cast<const float4*>(z2 + (size_t)src * 4);
    z.x *= w; z.y *= w; z.z *= w; z.w *= w;
    unsigned slot = atomicAdd(&cur2[dst], 1u);
    msg2[slot] = z;
  }
}

// conv2 aggregate: node n sums its contiguous msg2 range; embeds = relu(+r2)
__global__ __launch_bounds__(256) void k_conv2agg(
    const float4* __restrict__ msg2, const unsigned* __restrict__ nbase,
    const float* __restrict__ r2, float* __restrict__ embeds) {
  const size_t n = (size_t)blockIdx.x * 256 + threadIdx.x;
  const unsigned d0 = nbase[n], d1 = nbase[n + 1];
  float4 s = make_float4(0.f, 0.f, 0.f, 0.f);
  for (unsigned j = d0; j < d1; ++j) {
    float4 m = msg2[j];
    s.x += m.x; s.y += m.y; s.z += m.z; s.w += m.w;
  }
  const float4 rr = *reinterpret_cast<const float4*>(r2 + n * 4);
  float4 o;
  o.x = fmaxf(s.x + rr.x, 0.f);
  o.y = fmaxf(s.y + rr.y, 0.f);
  o.z = fmaxf(s.z + rr.z, 0.f);
  o.w = fmaxf(s.w + rr.w, 0.f);
  *reinterpret_cast<float4*>(embeds + n * 4) = o;
}

// ===========================================================================
// FALLBACK PATH (round-8 pipeline, used if ws_size is too small)
// ===========================================================================
__global__ __launch_bounds__(256) void k_hist(const int* __restrict__ ei,
                                              unsigned* __restrict__ hist) {
  unsigned e = blockIdx.x * 256u + threadIdx.x;
  unsigned d = (unsigned)ei[NE + e];
  atomicAdd(&hist[d >> 8], 1u);
}

__global__ __launch_bounds__(1024) void k_scan(const unsigned* __restrict__ hist,
                                               unsigned* __restrict__ base,
                                               unsigned* __restrict__ cursor) {
  __shared__ unsigned s[1024];
  const int tid = threadIdx.x;
  unsigned loc[7]; unsigned run = 0;
#pragma unroll
  for (int j = 0; j < 7; ++j) {
    int idx = tid * 7 + j;
    unsigned v = (idx < NBK) ? hist[idx] : 0u;
    loc[j] = run; run += v;
  }
  s[tid] = run; __syncthreads();
  for (int off = 1; off < 1024; off <<= 1) {
    unsigned t = (tid >= off) ? s[tid - off] : 0u;
    __syncthreads(); s[tid] += t; __syncthreads();
  }
  unsigned cb = tid ? s[tid - 1] : 0u;
#pragma unroll
  for (int j = 0; j < 7; ++j) {
    int idx = tid * 7 + j;
    if (idx < NBK) { unsigned b = cb + loc[j]; base[idx] = b; cursor[idx] = b; }
  }
  if (tid == 1023) base[NBK] = s[1023];
}

__global__ __launch_bounds__(256) void k_place(const int* __restrict__ ei,
                                               const float* __restrict__ ea,
                                               unsigned* __restrict__ cursor,
                                               uint2* __restrict__ rec) {
  unsigned e = blockIdx.x * 256u + threadIdx.x;
  unsigned s = (unsigned)ei[e];
  unsigned d = (unsigned)ei[NE + e];
  float w = ea[e];
  unsigned pos = atomicAdd(&cursor[d >> 8], 1u);
  rec[pos] = make_uint2(s | ((d & 255u) << 21), __float_as_uint(w));
}

__global__ __launch_bounds__(256) void k_conv1(
    const uint2* __restrict__ rec, const unsigned* __restrict__ base,
    const float* __restrict__ x,
    const float* __restrict__ W1_rel, const float* __restrict__ b1,
    const float* __restrict__ W1_root,
    const float* __restrict__ W2_rel, const float* __restrict__ b2,
    const float* __restrict__ W2_root,
    float* __restrict__ z2, float* __restrict__ r2, unsigned bkoff) {
  __shared__ float acc[RB * STR1];
  const int tid = threadIdx.x;
  const unsigned bk = blockIdx.x + bkoff;
  for (int i = tid; i < RB * STR1; i += 256) acc[i] = 0.f;
  __syncthreads();
  const unsigned r0 = base[bk], r1 = base[bk + 1];
  for (unsigned i = r0 + tid; i < r1; i += 256u) {
    uint2 rv = rec[i];
    const float4* xp = reinterpret_cast<const float4*>(x + (size_t)(rv.x & SRCM) * 16);
    float4 v0 = xp[0]; float4 v1 = xp[1]; float4 v2 = xp[2]; float4 v3 = xp[3];
    float w = __uint_as_float(rv.y);
    float* dp = acc + (rv.x >> 21) * STR1;
    atomicAdd(dp + 0,  v0.x * w); atomicAdd(dp + 1,  v0.y * w);
    atomicAdd(dp + 2,  v0.z * w); atomicAdd(dp + 3,  v0.w * w);
    atomicAdd(dp + 4,  v1.x * w); atomicAdd(dp + 5,  v1.y * w);
    atomicAdd(dp + 6,  v1.z * w); atomicAdd(dp + 7,  v1.w * w);
    atomicAdd(dp + 8,  v2.x * w); atomicAdd(dp + 9,  v2.y * w);
    atomicAdd(dp + 10, v2.z * w); atomicAdd(dp + 11, v2.w * w);
    atomicAdd(dp + 12, v3.x * w); atomicAdd(dp + 13, v3.y * w);
    atomicAdd(dp + 14, v3.z * w); atomicAdd(dp + 15, v3.w * w);
  }
  __syncthreads();
  size_t n = (size_t)bk * RB + tid;
  float a[16], xv[16];
  {
    const float4* xp = reinterpret_cast<const float4*>(x + n * 16);
#pragma unroll
    for (int q = 0; q < 4; ++q) {
      float4 t2 = xp[q];
      xv[4*q+0] = t2.x; xv[4*q+1] = t2.y; xv[4*q+2] = t2.z; xv[4*q+3] = t2.w;
    }
#pragma unroll
    for (int i = 0; i < 16; ++i) a[i] = acc[tid * STR1 + i];
  }
  float h[DH];
#pragma unroll
  for (int j = 0; j < DH; ++j) h[j] = b1[j];
#pragma unroll
  for (int i = 0; i < DIN; ++i) {
    float ai = a[i], xi = xv[i];
#pragma unroll
    for (int j = 0; j < DH; ++j)
      h[j] = fmaf(ai, W1_rel[i * DH + j], fmaf(xi, W1_root[i * DH + j], h[j]));
  }
#pragma unroll
  for (int j = 0; j < DH; ++j) h[j] = fmaxf(h[j], 0.f);
  float z[4] = {0.f, 0.f, 0.f, 0.f};
  float r[4] = {b2[0], b2[1], b2[2], b2[3]};
#pragma unroll
  for (int j = 0; j < DH; ++j) {
    float hj = h[j];
#pragma unroll
    for (int k = 0; k < 4; ++k) {
      z[k] = fmaf(hj, W2_rel[j * 4 + k], z[k]);
      r[k] = fmaf(hj, W2_root[j * 4 + k], r[k]);
    }
  }
  *reinterpret_cast<float4*>(z2 + n * 4) = make_float4(z[0], z[1], z[2], z[3]);
  *reinterpret_cast<float4*>(r2 + n * 4) = make_float4(r[0], r[1], r[2], r[3]);
}

__global__ __launch_bounds__(256) void k_conv2(
    const uint2* __restrict__ rec, const unsigned* __restrict__ base,
    const float* __restrict__ z2, const float* __restrict__ r2,
    float* __restrict__ embeds) {
  __shared__ float acc[RB2 * STR2];
  const int tid = threadIdx.x;
  const unsigned bk = blockIdx.x;
  for (int i = tid; i < RB2 * STR2; i += 256) acc[i] = 0.f;
  __syncthreads();
  const unsigned q0 = base[4 * bk + 0];
  const unsigned c1 = base[4 * bk + 1];
  const unsigned c2 = base[4 * bk + 2];
  const unsigned c3 = base[4 * bk + 3];
  const unsigned q4 = base[4 * bk + 4];
  const unsigned cnt = q4 - q0;
  if (cnt) {
    const unsigned last = q4 - 1u;
    const unsigned nch = (cnt + 1023u) >> 10;
    for (unsigned c = 0; c < nch; ++c) {
      const unsigned i0 = q0 + c * 1024u + tid;
      const unsigned i1 = i0 + 256u, i2 = i0 + 512u, i3 = i0 + 768u;
      const bool b0 = i0 < q4, b1v = i1 < q4, b2v = i2 < q4, b3v = i3 < q4;
      const unsigned j0 = b0  ? i0 : last;
      const unsigned j1 = b1v ? i1 : last;
      const unsigned j2 = b2v ? i2 : last;
      const unsigned j3 = b3v ? i3 : last;
      uint2 ra = rec[j0]; uint2 rb = rec[j1]; uint2 rc = rec[j2]; uint2 rd = rec[j3];
      const float4 za = *reinterpret_cast<const float4*>(z2 + (size_t)(ra.x & SRCM) * 4);
      const float4 zb = *reinterpret_cast<const float4*>(z2 + (size_t)(rb.x & SRCM) * 4);
      const float4 zc = *reinterpret_cast<const float4*>(z2 + (size_t)(rc.x & SRCM) * 4);
      const float4 zd = *reinterpret_cast<const float4*>(z2 + (size_t)(rd.x & SRCM) * 4);
      const float wa = b0  ? __uint_as_float(ra.y) : 0.f;
      const float wb = b1v ? __uint_as_float(rb.y) : 0.f;
      const float wc = b2v ? __uint_as_float(rc.y) : 0.f;
      const float wd = b3v ? __uint_as_float(rd.y) : 0.f;
      const unsigned sa = (unsigned)(j0 >= c1) + (j0 >= c2) + (j0 >= c3);
      const unsigned sb = (unsigned)(j1 >= c1) + (j1 >= c2) + (j1 >= c3);
      const unsigned sc = (unsigned)(j2 >= c1) + (j2 >= c2) + (j2 >= c3);
      const unsigned sd = (unsigned)(j3 >= c1) + (j3 >= c2) + (j3 >= c3);
      float* da = acc + (sa * 256u + (ra.x >> 21)) * STR2;
      float* db = acc + (sb * 256u + (rb.x >> 21)) * STR2;
      float* dc = acc + (sc * 256u + (rc.x >> 21)) * STR2;
      float* dd = acc + (sd * 256u + (rd.x >> 21)) * STR2;
      atomicAdd(da + 0, za.x * wa); atomicAdd(da + 1, za.y * wa);
      atomicAdd(da + 2, za.z * wa); atomicAdd(da + 3, za.w * wa);
      atomicAdd(db + 0, zb.x * wb); atomicAdd(db + 1, zb.y * wb);
      atomicAdd(db + 2, zb.z * wb); atomicAdd(db + 3, zb.w * wb);
      atomicAdd(dc + 0, zc.x * wc); atomicAdd(dc + 1, zc.y * wc);
      atomicAdd(dc + 2, zc.z * wc); atomicAdd(dc + 3, zc.w * wc);
      atomicAdd(dd + 0, zd.x * wd); atomicAdd(dd + 1, zd.y * wd);
      atomicAdd(dd + 2, zd.z * wd); atomicAdd(dd + 3, zd.w * wd);
    }
  }
  __syncthreads();
#pragma unroll
  for (int q = 0; q < 4; ++q) {
    const int m = q * 256 + tid;
    const size_t n = (size_t)bk * RB2 + m;
    const float4 rr = *reinterpret_cast<const float4*>(r2 + n * 4);
    float4 o;
    o.x = fmaxf(acc[m * STR2 + 0] + rr.x, 0.f);
    o.y = fmaxf(acc[m * STR2 + 1] + rr.y, 0.f);
    o.z = fmaxf(acc[m * STR2 + 2] + rr.z, 0.f);
    o.w = fmaxf(acc[m * STR2 + 3] + rr.w, 0.f);
    *reinterpret_cast<float4*>(embeds + n * 4) = o;
  }
}

// ---------------------------------------------------------------------------
// Final MLP (shared by both paths)
// ---------------------------------------------------------------------------
__global__ __launch_bounds__(256) void k_final(
    const float* __restrict__ embeds, const float* __restrict__ gfeat,
    const float* __restrict__ Wg1, const float* __restrict__ bg1,
    const float* __restrict__ Wg2, const float* __restrict__ bg2,
    const float* __restrict__ Wg3, const float* __restrict__ bg3,
    const float* __restrict__ Wo1, const float* __restrict__ bo1,
    const float* __restrict__ Wo2, const float* __restrict__ bo2,
    const float* __restrict__ Wo3, const float* __restrict__ bo3,
    float* __restrict__ out) {
  __shared__ float smem[TB * 232 + TB * 128];
  float* svec  = smem;
  float* sbuf1 = smem + TB * 232;
  float* sbuf2 = smem;
  const int tid = threadIdx.x;
  const int b0  = blockIdx.x * TB;
  {
    const size_t gbase = (size_t)b0 * 216;
    for (int idx = tid; idx < TB * 216; idx += 256) {
      int b = idx / 216;
      int k = idx - b * 216;
      svec[b * 232 + k] = embeds[gbase + idx];
    }
  }
  if (tid < TB) {
    const float* gf = gfeat + (size_t)(b0 + tid) * GLOBF;
    float gin[16];
#pragma unroll
    for (int i = 0; i < 16; ++i) gin[i] = gf[i];
    float g1[8];
#pragma unroll
    for (int j = 0; j < 8; ++j) {
      float acc = bg1[j];
#pragma unroll
      for (int i = 0; i < 16; ++i) acc = fmaf(gin[i], Wg1[i * 8 + j], acc);
      g1[j] = fmaxf(acc, 0.f);
    }
    float g2[8];
#pragma unroll
    for (int j = 0; j < 8; ++j) {
      float acc = bg2[j];
#pragma unroll
      for (int i = 0; i < 8; ++i) acc = fmaf(g1[i], Wg2[i * 8 + j], acc);
      g2[j] = fmaxf(acc, 0.f);
    }
#pragma unroll
    for (int j = 0; j < 16; ++j) {
      float acc = bg3[j];
#pragma unroll
      for (int i = 0; i < 8; ++i) acc = fmaf(g2[i], Wg3[i * 16 + j], acc);
      svec[tid * 232 + 216 + j] = fmaxf(acc, 0.f);
    }
  }
  __syncthreads();
  const int c0 = (tid & 31) * 4;
  const int rb = (tid >> 5) * 4;
  {
    float acc[4][4];
#pragma unroll
    for (int r = 0; r < 4; ++r)
#pragma unroll
      for (int c = 0; c < 4; ++c) acc[r][c] = 0.f;
#pragma unroll 4
    for (int i = 0; i < 232; ++i) {
      const float4 w = *reinterpret_cast<const float4*>(Wo1 + (size_t)i * 128 + c0);
#pragma unroll
      for (int r = 0; r < 4; ++r) {
        float v = svec[(rb + r) * 232 + i];
        acc[r][0] = fmaf(v, w.x, acc[r][0]);
        acc[r][1] = fmaf(v, w.y, acc[r][1]);
        acc[r][2] = fmaf(v, w.z, acc[r][2]);
        acc[r][3] = fmaf(v, w.w, acc[r][3]);
      }
    }
    const float4 bv = *reinterpret_cast<const float4*>(bo1 + c0);
#pragma unroll
    for (int r = 0; r < 4; ++r) {
      float4 o;
      o.x = fmaxf(acc[r][0] + bv.x, 0.f);
      o.y = fmaxf(acc[r][1] + bv.y, 0.f);
      o.z = fmaxf(acc[r][2] + bv.z, 0.f);
      o.w = fmaxf(acc[r][3] + bv.w, 0.f);
      *reinterpret_cast<float4*>(sbuf1 + (rb + r) * 128 + c0) = o;
    }
  }
  __syncthreads();
  {
    float acc[4][4];
#pragma unroll
    for (int r = 0; r < 4; ++r)
#pragma unroll
      for (int c = 0; c < 4; ++c) acc[r][c] = 0.f;
#pragma unroll 4
    for (int i = 0; i < 128; ++i) {
      const float4 w = *reinterpret_cast<const float4*>(Wo2 + (size_t)i * 128 + c0);
#pragma unroll
      for (int r = 0; r < 4; ++r) {
        float v = sbuf1[(rb + r) * 128 + i];
        acc[r][0] = fmaf(v, w.x, acc[r][0]);
        acc[r][1] = fmaf(v, w.y, acc[r][1]);
        acc[r][2] = fmaf(v, w.z, acc[r][2]);
        acc[r][3] = fmaf(v, w.w, acc[r][3]);
      }
    }
    const float4 bv = *reinterpret_cast<const float4*>(bo2 + c0);
#pragma unroll
    for (int r = 0; r < 4; ++r) {
      float4 o;
      o.x = fmaxf(acc[r][0] + bv.x, 0.f);
      o.y = fmaxf(acc[r][1] + bv.y, 0.f);
      o.z = fmaxf(acc[r][2] + bv.z, 0.f);
      o.w = fmaxf(acc[r][3] + bv.w, 0.f);
      *reinterpret_cast<float4*>(sbuf2 + (rb + r) * 128 + c0) = o;
    }
  }
  __syncthreads();
  {
    const int c2 = (tid & 31) * 2;
    float acc[4][2];
#pragma unroll
    for (int r = 0; r < 4; ++r) { acc[r][0] = 0.f; acc[r][1] = 0.f; }
#pragma unroll 4
    for (int i = 0; i < 128; ++i) {
      const float2 w = *reinterpret_cast<const float2*>(Wo3 + (size_t)i * 64 + c2);
#pragma unroll
      for (int r = 0; r < 4; ++r) {
        float v = sbuf2[(rb + r) * 128 + i];
        acc[r][0] = fmaf(v, w.x, acc[r][0]);
        acc[r][1] = fmaf(v, w.y, acc[r][1]);
      }
    }
    const float2 bv = *reinterpret_cast<const float2*>(bo3 + c2);
#pragma unroll
    for (int r = 0; r < 4; ++r) {
      float2 o;
      o.x = acc[r][0] + bv.x;
      o.y = acc[r][1] + bv.y;
      *reinterpret_cast<float2*>(out + (size_t)(b0 + rb + r) * 64 + c2) = o;
    }
  }
}

// ---------------------------------------------------------------------------
extern "C" void kernel_launch(void* const* d_in, const int* in_sizes, int n_in,
                              void* d_out, int out_size, void* d_ws, size_t ws_size,
                              hipStream_t stream) {
  const float* x      = (const float*)d_in[0];
  const int*   ei     = (const int*)d_in[1];
  const float* ea     = (const float*)d_in[2];
  const float* gfeat  = (const float*)d_in[3];
  const float* W1_rel = (const float*)d_in[5];
  const float* b1     = (const float*)d_in[6];
  const float* W1_root= (const float*)d_in[7];
  const float* W2_rel = (const float*)d_in[8];
  const float* b2     = (const float*)d_in[9];
  const float* W2_root= (const float*)d_in[10];
  const float* Wg1 = (const float*)d_in[11];
  const float* bg1 = (const float*)d_in[12];
  const float* Wg2 = (const float*)d_in[13];
  const float* bg2 = (const float*)d_in[14];
  const float* Wg3 = (const float*)d_in[15];
  const float* bg3 = (const float*)d_in[16];
  const float* Wo1 = (const float*)d_in[17];
  const float* bo1 = (const float*)d_in[18];
  const float* Wo2 = (const float*)d_in[19];
  const float* bo2 = (const float*)d_in[20];
  const float* Wo3 = (const float*)d_in[21];
  const float* bo3 = (const float*)d_in[22];
  float* outp = (float*)d_out;

  // ---- new-path workspace layout (~446 MB) ----
  float*    msg1   = (float*)d_ws;                        // NE*16 f (msg2 overlays)
  uint2*    rec_s  = (uint2*)(msg1 + (size_t)NE * 16);    // NE * 8B
  float*    z2     = (float*)(rec_s + NE);                // NN*4 f
  float*    r2     = z2 + (size_t)NN * 4;                 // NN*4 f
  float*    embeds = r2 + (size_t)NN * 4;                 // NN*4 f
  unsigned* nbase  = (unsigned*)(embeds + (size_t)NN * 4);// NN+16
  unsigned* cur1   = nbase + NN + 16;                     // NN
  unsigned* cur2   = cur1 + NN;                           // NN (also hist_dstnode)
  unsigned* hist_src   = cur2 + NN;                       // NSB
  unsigned* base_src   = hist_src + NSB;                  // NSB+1
  unsigned* cursor_src = base_src + NSB + 1;              // NSB
  unsigned* bsum   = cursor_src + NSB;                    // NSCB
  unsigned* bsumx  = bsum + NSCB;                         // NSCB
  size_t req = (size_t)((char*)(bsumx + NSCB) - (char*)d_ws);

  if (ws_size >= req) {
    // ============== write-routed CSR message-push path ==============
    hipMemsetAsync(cur2, 0, (size_t)NN * sizeof(unsigned), stream);   // dst-node counts
    hipMemsetAsync(hist_src, 0, NSB * sizeof(unsigned), stream);
    k_hist2   <<<NE / 256, 256, 0, stream>>>(ei, cur2, hist_src);
    k_scan_src<<<1, 1024, 0, stream>>>(hist_src, base_src, cursor_src);
    k_scanA   <<<NSCB, 1024, 0, stream>>>(cur2, nbase, bsum);
    k_scanB   <<<1, 1024, 0, stream>>>(bsum, bsumx);
    k_scanC   <<<NSCB, 1024, 0, stream>>>(nbase, bsumx, cur1, cur2);
    k_place_src<<<NE / 256, 256, 0, stream>>>(ei, ea, cursor_src, rec_s);
    k_msg1    <<<NSB, 256, 0, stream>>>(rec_s, base_src, x, cur1, (float4*)msg1);
    k_conv1agg<<<NN / 256, 256, 0, stream>>>((const float4*)msg1, nbase, x,
                                             W1_rel, b1, W1_root,
                                             W2_rel, b2, W2_root, z2, r2);
    k_msg2    <<<NSB, 256, 0, stream>>>(rec_s, base_src, z2, cur2, (float4*)msg1);
    k_conv2agg<<<NN / 256, 256, 0, stream>>>((const float4*)msg1, nbase, r2, embeds);
    k_final   <<<BD / TB, 256, 0, stream>>>(embeds, gfeat,
                                            Wg1, bg1, Wg2, bg2, Wg3, bg3,
                                            Wo1, bo1, Wo2, bo2, Wo3, bo3, outp);
  } else {
    // ============== fallback: round-8 pipeline (~123 MB) ==============
    uint2*    rec    = (uint2*)d_ws;
    float*    fz2    = (float*)(rec + NE);
    float*    fr2    = fz2 + (size_t)NN * 4;
    float*    femb   = fr2 + (size_t)NN * 4;
    unsigned* hist   = (unsigned*)(femb + (size_t)NN * 4);
    unsigned* fbase  = hist + NBK;
    unsigned* fcur   = fbase + NBK + 1;

    hipMemsetAsync(hist, 0, NBK * sizeof(unsigned), stream);
    k_hist <<<NE / 256, 256, 0, stream>>>(ei, hist);
    k_scan <<<1, 1024, 0, stream>>>(hist, fbase, fcur);
    k_place<<<NE / 256, 256, 0, stream>>>(ei, ea, fcur, rec);
    for (unsigned q = 0; q < 4; ++q)
      k_conv1<<<QBK, 256, 0, stream>>>(rec, fbase, x, W1_rel, b1, W1_root,
                                       W2_rel, b2, W2_root, fz2, fr2, q * QBK);
    k_conv2<<<NBK2, 256, 0, stream>>>(rec, fbase, fz2, fr2, femb);
    k_final<<<BD / TB, 256, 0, stream>>>(femb, gfeat,
                                         Wg1, bg1, Wg2, bg2, Wg3, bg3,
                                         Wo1, bo1, Wo2, bo2, Wo3, bo3, outp);
  }
}

// Round 10
// 1629.673 us; speedup vs baseline: 1.0907x; 1.0907x over previous
//
#include <hip/hip_runtime.h>

// Problem constants
#define BD   32768
#define NPG  54
#define NN   (BD * NPG)          // 1,769,472 nodes
#define NE   (BD * 144)          // 4,718,592 edges
#define DIN  16
#define DH   32
#define GLOBF 16
#define TB   32
#define RB   256                 // nodes per bucket (both src and dst)
#define NBK  (NN / RB)           // 6912 buckets
#define QBK  (NBK / 4)
#define RB2  1024
#define NBK2 (NN / RB2)
#define STR1 17                  // LDS row stride conv1 tile
#define STR2 5                   // LDS row stride conv2 tile
#define SRCM 0x1FFFFFu

// ===========================================================================
// WRITE-ROUTED PATH: src-sorted records, dst-bucket message push
// ===========================================================================

// combined histograms over src buckets and dst buckets (one ei pass)
__global__ __launch_bounds__(256) void k_histAB(const int* __restrict__ ei,
                                                unsigned* __restrict__ hist_s,
                                                unsigned* __restrict__ hist_d) {
  unsigned e = blockIdx.x * 256u + threadIdx.x;
  unsigned s = (unsigned)ei[e];
  unsigned d = (unsigned)ei[NE + e];
  atomicAdd(&hist_s[s >> 8], 1u);
  atomicAdd(&hist_d[d >> 8], 1u);
}

// exclusive scan of 6912 counts (single block) -> base, cursor
__global__ __launch_bounds__(1024) void k_scan(const unsigned* __restrict__ hist,
                                               unsigned* __restrict__ base,
                                               unsigned* __restrict__ cursor) {
  __shared__ unsigned s[1024];
  const int tid = threadIdx.x;
  unsigned loc[7]; unsigned run = 0;
#pragma unroll
  for (int j = 0; j < 7; ++j) {
    int idx = tid * 7 + j;
    unsigned v = (idx < NBK) ? hist[idx] : 0u;
    loc[j] = run; run += v;
  }
  s[tid] = run; __syncthreads();
  for (int off = 1; off < 1024; off <<= 1) {
    unsigned t = (tid >= off) ? s[tid - off] : 0u;
    __syncthreads(); s[tid] += t; __syncthreads();
  }
  unsigned cb = tid ? s[tid - 1] : 0u;
#pragma unroll
  for (int j = 0; j < 7; ++j) {
    int idx = tid * 7 + j;
    if (idx < NBK) { unsigned b = cb + loc[j]; base[idx] = b; cursor[idx] = b; }
  }
  if (tid == 1023) base[NBK] = s[1023];                  // = NE
}

// place edges sorted by SRC bucket: rec = {src_lo:8 | dst<<8, w}
__global__ __launch_bounds__(256) void k_place_src(const int* __restrict__ ei,
                                                   const float* __restrict__ ea,
                                                   unsigned* __restrict__ scur,
                                                   uint2* __restrict__ rec) {
  unsigned e = blockIdx.x * 256u + threadIdx.x;
  unsigned s = (unsigned)ei[e];
  unsigned d = (unsigned)ei[NE + e];
  float w = ea[e];
  unsigned pos = atomicAdd(&scur[s >> 8], 1u);
  rec[pos] = make_uint2((s & 255u) | (d << 8), __float_as_uint(w));
}

// msg1 push: per src bucket (x window 16KB, L1-resident) push w*x[src] (64B)
// to a dst-BUCKET slot; record node-in-bucket in dlo; remember slot in slotmap.
__global__ __launch_bounds__(256) void k_msg1(
    const uint2* __restrict__ rec, const unsigned* __restrict__ sbase,
    const float* __restrict__ x, unsigned* __restrict__ dcur,
    float4* __restrict__ msg1, unsigned char* __restrict__ dlo,
    unsigned* __restrict__ slotmap) {
  const unsigned bk = blockIdx.x;
  const unsigned r0 = sbase[bk], r1 = sbase[bk + 1];
  const unsigned nb = bk << 8;
  for (unsigned i = r0 + threadIdx.x; i < r1; i += 256u) {
    uint2 rv = rec[i];
    unsigned src = nb + (rv.x & 255u);
    unsigned dst = rv.x >> 8;
    float w = __uint_as_float(rv.y);
    const float4* xp = reinterpret_cast<const float4*>(x + (size_t)src * 16);
    float4 v0 = xp[0], v1 = xp[1], v2 = xp[2], v3 = xp[3];
    unsigned slot = atomicAdd(&dcur[dst >> 8], 1u);
    v0.x *= w; v0.y *= w; v0.z *= w; v0.w *= w;
    v1.x *= w; v1.y *= w; v1.z *= w; v1.w *= w;
    v2.x *= w; v2.y *= w; v2.z *= w; v2.w *= w;
    v3.x *= w; v3.y *= w; v3.z *= w; v3.w *= w;
    float4* mp = msg1 + (size_t)slot * 4;
    mp[0] = v0; mp[1] = v1; mp[2] = v2; mp[3] = v3;
    dlo[slot] = (unsigned char)(dst & 255u);
    slotmap[i] = slot;
  }
}

// conv1 aggregate: per dst bucket, contiguous msg reads -> LDS atomic tile,
// then fused node transform -> z2, r2
__global__ __launch_bounds__(256) void k_conv1agg(
    const float4* __restrict__ msg1, const unsigned char* __restrict__ dlo,
    const unsigned* __restrict__ dbase, const float* __restrict__ x,
    const float* __restrict__ W1_rel, const float* __restrict__ b1,
    const float* __restrict__ W1_root,
    const float* __restrict__ W2_rel, const float* __restrict__ b2,
    const float* __restrict__ W2_root,
    float* __restrict__ z2, float* __restrict__ r2) {
  __shared__ float acc[RB * STR1];                       // 17408 B
  const int tid = threadIdx.x;
  const unsigned bk = blockIdx.x;
  for (int i = tid; i < RB * STR1; i += 256) acc[i] = 0.f;
  __syncthreads();

  const unsigned r0 = dbase[bk], r1 = dbase[bk + 1];
  for (unsigned i = r0 + tid; i < r1; i += 256u) {
    const float4* mp = msg1 + (size_t)i * 4;
    float4 m0 = mp[0], m1 = mp[1], m2 = mp[2], m3 = mp[3];
    float* dp = acc + (unsigned)dlo[i] * STR1;
    atomicAdd(dp + 0,  m0.x); atomicAdd(dp + 1,  m0.y);
    atomicAdd(dp + 2,  m0.z); atomicAdd(dp + 3,  m0.w);
    atomicAdd(dp + 4,  m1.x); atomicAdd(dp + 5,  m1.y);
    atomicAdd(dp + 6,  m1.z); atomicAdd(dp + 7,  m1.w);
    atomicAdd(dp + 8,  m2.x); atomicAdd(dp + 9,  m2.y);
    atomicAdd(dp + 10, m2.z); atomicAdd(dp + 11, m2.w);
    atomicAdd(dp + 12, m3.x); atomicAdd(dp + 13, m3.y);
    atomicAdd(dp + 14, m3.z); atomicAdd(dp + 15, m3.w);
  }
  __syncthreads();

  size_t n = (size_t)bk * RB + tid;
  float a[16], xv[16];
  {
    const float4* xp = reinterpret_cast<const float4*>(x + n * 16);
#pragma unroll
    for (int q = 0; q < 4; ++q) {
      float4 t2 = xp[q];
      xv[4*q+0] = t2.x; xv[4*q+1] = t2.y; xv[4*q+2] = t2.z; xv[4*q+3] = t2.w;
    }
#pragma unroll
    for (int i = 0; i < 16; ++i) a[i] = acc[tid * STR1 + i];
  }
  float h[DH];
#pragma unroll
  for (int j = 0; j < DH; ++j) h[j] = b1[j];
#pragma unroll
  for (int i = 0; i < DIN; ++i) {
    float ai = a[i], xi = xv[i];
#pragma unroll
    for (int j = 0; j < DH; ++j)
      h[j] = fmaf(ai, W1_rel[i * DH + j], fmaf(xi, W1_root[i * DH + j], h[j]));
  }
#pragma unroll
  for (int j = 0; j < DH; ++j) h[j] = fmaxf(h[j], 0.f);
  float z[4] = {0.f, 0.f, 0.f, 0.f};
  float r[4] = {b2[0], b2[1], b2[2], b2[3]};
#pragma unroll
  for (int j = 0; j < DH; ++j) {
    float hj = h[j];
#pragma unroll
    for (int k = 0; k < 4; ++k) {
      z[k] = fmaf(hj, W2_rel[j * 4 + k], z[k]);
      r[k] = fmaf(hj, W2_root[j * 4 + k], r[k]);
    }
  }
  *reinterpret_cast<float4*>(z2 + n * 4) = make_float4(z[0], z[1], z[2], z[3]);
  *reinterpret_cast<float4*>(r2 + n * 4) = make_float4(r[0], r[1], r[2], r[3]);
}

// msg2 push: reuse slot assignment via slotmap (no cursor atomics, no dlo2)
__global__ __launch_bounds__(256) void k_msg2(
    const uint2* __restrict__ rec, const unsigned* __restrict__ sbase,
    const float* __restrict__ z2, const unsigned* __restrict__ slotmap,
    float4* __restrict__ msg2) {
  const unsigned bk = blockIdx.x;
  const unsigned r0 = sbase[bk], r1 = sbase[bk + 1];
  const unsigned nb = bk << 8;
  for (unsigned i = r0 + threadIdx.x; i < r1; i += 256u) {
    uint2 rv = rec[i];
    unsigned src = nb + (rv.x & 255u);
    float w = __uint_as_float(rv.y);
    float4 z = *reinterpret_cast<const float4*>(z2 + (size_t)src * 4);
    z.x *= w; z.y *= w; z.z *= w; z.w *= w;
    msg2[slotmap[i]] = z;
  }
}

// conv2 aggregate: contiguous msg2 reads -> LDS tile; embeds = relu(acc + r2)
__global__ __launch_bounds__(256) void k_conv2agg(
    const float4* __restrict__ msg2, const unsigned char* __restrict__ dlo,
    const unsigned* __restrict__ dbase, const float* __restrict__ r2,
    float* __restrict__ embeds) {
  __shared__ float acc[RB * STR2];                       // 5120 B
  const int tid = threadIdx.x;
  const unsigned bk = blockIdx.x;
  for (int i = tid; i < RB * STR2; i += 256) acc[i] = 0.f;
  __syncthreads();
  const unsigned r0 = dbase[bk], r1 = dbase[bk + 1];
  for (unsigned i = r0 + tid; i < r1; i += 256u) {
    float4 m = msg2[i];
    float* dp = acc + (unsigned)dlo[i] * STR2;
    atomicAdd(dp + 0, m.x); atomicAdd(dp + 1, m.y);
    atomicAdd(dp + 2, m.z); atomicAdd(dp + 3, m.w);
  }
  __syncthreads();
  size_t n = (size_t)bk * RB + tid;
  const float4 rr = *reinterpret_cast<const float4*>(r2 + n * 4);
  float4 o;
  o.x = fmaxf(acc[tid * STR2 + 0] + rr.x, 0.f);
  o.y = fmaxf(acc[tid * STR2 + 1] + rr.y, 0.f);
  o.z = fmaxf(acc[tid * STR2 + 2] + rr.z, 0.f);
  o.w = fmaxf(acc[tid * STR2 + 3] + rr.w, 0.f);
  *reinterpret_cast<float4*>(embeds + n * 4) = o;
}

// ===========================================================================
// FALLBACK PATH (round-8 pipeline) — used only if ws_size is too small
// ===========================================================================
__global__ __launch_bounds__(256) void k_place(const int* __restrict__ ei,
                                               const float* __restrict__ ea,
                                               unsigned* __restrict__ cursor,
                                               uint2* __restrict__ rec) {
  unsigned e = blockIdx.x * 256u + threadIdx.x;
  unsigned s = (unsigned)ei[e];
  unsigned d = (unsigned)ei[NE + e];
  float w = ea[e];
  unsigned pos = atomicAdd(&cursor[d >> 8], 1u);
  rec[pos] = make_uint2(s | ((d & 255u) << 21), __float_as_uint(w));
}

__global__ __launch_bounds__(256) void k_conv1(
    const uint2* __restrict__ rec, const unsigned* __restrict__ base,
    const float* __restrict__ x,
    const float* __restrict__ W1_rel, const float* __restrict__ b1,
    const float* __restrict__ W1_root,
    const float* __restrict__ W2_rel, const float* __restrict__ b2,
    const float* __restrict__ W2_root,
    float* __restrict__ z2, float* __restrict__ r2, unsigned bkoff) {
  __shared__ float acc[RB * STR1];
  const int tid = threadIdx.x;
  const unsigned bk = blockIdx.x + bkoff;
  for (int i = tid; i < RB * STR1; i += 256) acc[i] = 0.f;
  __syncthreads();
  const unsigned r0 = base[bk], r1 = base[bk + 1];
  for (unsigned i = r0 + tid; i < r1; i += 256u) {
    uint2 rv = rec[i];
    const float4* xp = reinterpret_cast<const float4*>(x + (size_t)(rv.x & SRCM) * 16);
    float4 v0 = xp[0]; float4 v1 = xp[1]; float4 v2 = xp[2]; float4 v3 = xp[3];
    float w = __uint_as_float(rv.y);
    float* dp = acc + (rv.x >> 21) * STR1;
    atomicAdd(dp + 0,  v0.x * w); atomicAdd(dp + 1,  v0.y * w);
    atomicAdd(dp + 2,  v0.z * w); atomicAdd(dp + 3,  v0.w * w);
    atomicAdd(dp + 4,  v1.x * w); atomicAdd(dp + 5,  v1.y * w);
    atomicAdd(dp + 6,  v1.z * w); atomicAdd(dp + 7,  v1.w * w);
    atomicAdd(dp + 8,  v2.x * w); atomicAdd(dp + 9,  v2.y * w);
    atomicAdd(dp + 10, v2.z * w); atomicAdd(dp + 11, v2.w * w);
    atomicAdd(dp + 12, v3.x * w); atomicAdd(dp + 13, v3.y * w);
    atomicAdd(dp + 14, v3.z * w); atomicAdd(dp + 15, v3.w * w);
  }
  __syncthreads();
  size_t n = (size_t)bk * RB + tid;
  float a[16], xv[16];
  {
    const float4* xp = reinterpret_cast<const float4*>(x + n * 16);
#pragma unroll
    for (int q = 0; q < 4; ++q) {
      float4 t2 = xp[q];
      xv[4*q+0] = t2.x; xv[4*q+1] = t2.y; xv[4*q+2] = t2.z; xv[4*q+3] = t2.w;
    }
#pragma unroll
    for (int i = 0; i < 16; ++i) a[i] = acc[tid * STR1 + i];
  }
  float h[DH];
#pragma unroll
  for (int j = 0; j < DH; ++j) h[j] = b1[j];
#pragma unroll
  for (int i = 0; i < DIN; ++i) {
    float ai = a[i], xi = xv[i];
#pragma unroll
    for (int j = 0; j < DH; ++j)
      h[j] = fmaf(ai, W1_rel[i * DH + j], fmaf(xi, W1_root[i * DH + j], h[j]));
  }
#pragma unroll
  for (int j = 0; j < DH; ++j) h[j] = fmaxf(h[j], 0.f);
  float z[4] = {0.f, 0.f, 0.f, 0.f};
  float r[4] = {b2[0], b2[1], b2[2], b2[3]};
#pragma unroll
  for (int j = 0; j < DH; ++j) {
    float hj = h[j];
#pragma unroll
    for (int k = 0; k < 4; ++k) {
      z[k] = fmaf(hj, W2_rel[j * 4 + k], z[k]);
      r[k] = fmaf(hj, W2_root[j * 4 + k], r[k]);
    }
  }
  *reinterpret_cast<float4*>(z2 + n * 4) = make_float4(z[0], z[1], z[2], z[3]);
  *reinterpret_cast<float4*>(r2 + n * 4) = make_float4(r[0], r[1], r[2], r[3]);
}

__global__ __launch_bounds__(256) void k_conv2(
    const uint2* __restrict__ rec, const unsigned* __restrict__ base,
    const float* __restrict__ z2, const float* __restrict__ r2,
    float* __restrict__ embeds) {
  __shared__ float acc[RB2 * STR2];
  const int tid = threadIdx.x;
  const unsigned bk = blockIdx.x;
  for (int i = tid; i < RB2 * STR2; i += 256) acc[i] = 0.f;
  __syncthreads();
  const unsigned q0 = base[4 * bk + 0];
  const unsigned c1 = base[4 * bk + 1];
  const unsigned c2 = base[4 * bk + 2];
  const unsigned c3 = base[4 * bk + 3];
  const unsigned q4 = base[4 * bk + 4];
  const unsigned cnt = q4 - q0;
  if (cnt) {
    const unsigned last = q4 - 1u;
    const unsigned nch = (cnt + 1023u) >> 10;
    for (unsigned c = 0; c < nch; ++c) {
      const unsigned i0 = q0 + c * 1024u + tid;
      const unsigned i1 = i0 + 256u, i2 = i0 + 512u, i3 = i0 + 768u;
      const bool b0 = i0 < q4, b1v = i1 < q4, b2v = i2 < q4, b3v = i3 < q4;
      const unsigned j0 = b0  ? i0 : last;
      const unsigned j1 = b1v ? i1 : last;
      const unsigned j2 = b2v ? i2 : last;
      const unsigned j3 = b3v ? i3 : last;
      uint2 ra = rec[j0]; uint2 rb = rec[j1]; uint2 rc = rec[j2]; uint2 rd = rec[j3];
      const float4 za = *reinterpret_cast<const float4*>(z2 + (size_t)(ra.x & SRCM) * 4);
      const float4 zb = *reinterpret_cast<const float4*>(z2 + (size_t)(rb.x & SRCM) * 4);
      const float4 zc = *reinterpret_cast<const float4*>(z2 + (size_t)(rc.x & SRCM) * 4);
      const float4 zd = *reinterpret_cast<const float4*>(z2 + (size_t)(rd.x & SRCM) * 4);
      const float wa = b0  ? __uint_as_float(ra.y) : 0.f;
      const float wb = b1v ? __uint_as_float(rb.y) : 0.f;
      const float wc = b2v ? __uint_as_float(rc.y) : 0.f;
      const float wd = b3v ? __uint_as_float(rd.y) : 0.f;
      const unsigned sa = (unsigned)(j0 >= c1) + (j0 >= c2) + (j0 >= c3);
      const unsigned sb = (unsigned)(j1 >= c1) + (j1 >= c2) + (j1 >= c3);
      const unsigned sc = (unsigned)(j2 >= c1) + (j2 >= c2) + (j2 >= c3);
      const unsigned sd = (unsigned)(j3 >= c1) + (j3 >= c2) + (j3 >= c3);
      float* da = acc + (sa * 256u + (ra.x >> 21)) * STR2;
      float* db = acc + (sb * 256u + (rb.x >> 21)) * STR2;
      float* dc = acc + (sc * 256u + (rc.x >> 21)) * STR2;
      float* dd = acc + (sd * 256u + (rd.x >> 21)) * STR2;
      atomicAdd(da + 0, za.x * wa); atomicAdd(da + 1, za.y * wa);
      atomicAdd(da + 2, za.z * wa); atomicAdd(da + 3, za.w * wa);
      atomicAdd(db + 0, zb.x * wb); atomicAdd(db + 1, zb.y * wb);
      atomicAdd(db + 2, zb.z * wb); atomicAdd(db + 3, zb.w * wb);
      atomicAdd(dc + 0, zc.x * wc); atomicAdd(dc + 1, zc.y * wc);
      atomicAdd(dc + 2, zc.z * wc); atomicAdd(dc + 3, zc.w * wc);
      atomicAdd(dd + 0, zd.x * wd); atomicAdd(dd + 1, zd.y * wd);
      atomicAdd(dd + 2, zd.z * wd); atomicAdd(dd + 3, zd.w * wd);
    }
  }
  __syncthreads();
#pragma unroll
  for (int q = 0; q < 4; ++q) {
    const int m = q * 256 + tid;
    const size_t n = (size_t)bk * RB2 + m;
    const float4 rr = *reinterpret_cast<const float4*>(r2 + n * 4);
    float4 o;
    o.x = fmaxf(acc[m * STR2 + 0] + rr.x, 0.f);
    o.y = fmaxf(acc[m * STR2 + 1] + rr.y, 0.f);
    o.z = fmaxf(acc[m * STR2 + 2] + rr.z, 0.f);
    o.w = fmaxf(acc[m * STR2 + 3] + rr.w, 0.f);
    *reinterpret_cast<float4*>(embeds + n * 4) = o;
  }
}

// ---------------------------------------------------------------------------
// Final MLP (shared by both paths)
// ---------------------------------------------------------------------------
__global__ __launch_bounds__(256) void k_final(
    const float* __restrict__ embeds, const float* __restrict__ gfeat,
    const float* __restrict__ Wg1, const float* __restrict__ bg1,
    const float* __restrict__ Wg2, const float* __restrict__ bg2,
    const float* __restrict__ Wg3, const float* __restrict__ bg3,
    const float* __restrict__ Wo1, const float* __restrict__ bo1,
    const float* __restrict__ Wo2, const float* __restrict__ bo2,
    const float* __restrict__ Wo3, const float* __restrict__ bo3,
    float* __restrict__ out) {
  __shared__ float smem[TB * 232 + TB * 128];
  float* svec  = smem;
  float* sbuf1 = smem + TB * 232;
  float* sbuf2 = smem;
  const int tid = threadIdx.x;
  const int b0  = blockIdx.x * TB;
  {
    const size_t gbase = (size_t)b0 * 216;
    for (int idx = tid; idx < TB * 216; idx += 256) {
      int b = idx / 216;
      int k = idx - b * 216;
      svec[b * 232 + k] = embeds[gbase + idx];
    }
  }
  if (tid < TB) {
    const float* gf = gfeat + (size_t)(b0 + tid) * GLOBF;
    float gin[16];
#pragma unroll
    for (int i = 0; i < 16; ++i) gin[i] = gf[i];
    float g1[8];
#pragma unroll
    for (int j = 0; j < 8; ++j) {
      float acc = bg1[j];
#pragma unroll
      for (int i = 0; i < 16; ++i) acc = fmaf(gin[i], Wg1[i * 8 + j], acc);
      g1[j] = fmaxf(acc, 0.f);
    }
    float g2[8];
#pragma unroll
    for (int j = 0; j < 8; ++j) {
      float acc = bg2[j];
#pragma unroll
      for (int i = 0; i < 8; ++i) acc = fmaf(g1[i], Wg2[i * 8 + j], acc);
      g2[j] = fmaxf(acc, 0.f);
    }
#pragma unroll
    for (int j = 0; j < 16; ++j) {
      float acc = bg3[j];
#pragma unroll
      for (int i = 0; i < 8; ++i) acc = fmaf(g2[i], Wg3[i * 16 + j], acc);
      svec[tid * 232 + 216 + j] = fmaxf(acc, 0.f);
    }
  }
  __syncthreads();
  const int c0 = (tid & 31) * 4;
  const int rb = (tid >> 5) * 4;
  {
    float acc[4][4];
#pragma unroll
    for (int r = 0; r < 4; ++r)
#pragma unroll
      for (int c = 0; c < 4; ++c) acc[r][c] = 0.f;
#pragma unroll 4
    for (int i = 0; i < 232; ++i) {
      const float4 w = *reinterpret_cast<const float4*>(Wo1 + (size_t)i * 128 + c0);
#pragma unroll
      for (int r = 0; r < 4; ++r) {
        float v = svec[(rb + r) * 232 + i];
        acc[r][0] = fmaf(v, w.x, acc[r][0]);
        acc[r][1] = fmaf(v, w.y, acc[r][1]);
        acc[r][2] = fmaf(v, w.z, acc[r][2]);
        acc[r][3] = fmaf(v, w.w, acc[r][3]);
      }
    }
    const float4 bv = *reinterpret_cast<const float4*>(bo1 + c0);
#pragma unroll
    for (int r = 0; r < 4; ++r) {
      float4 o;
      o.x = fmaxf(acc[r][0] + bv.x, 0.f);
      o.y = fmaxf(acc[r][1] + bv.y, 0.f);
      o.z = fmaxf(acc[r][2] + bv.z, 0.f);
      o.w = fmaxf(acc[r][3] + bv.w, 0.f);
      *reinterpret_cast<float4*>(sbuf1 + (rb + r) * 128 + c0) = o;
    }
  }
  __syncthreads();
  {
    float acc[4][4];
#pragma unroll
    for (int r = 0; r < 4; ++r)
#pragma unroll
      for (int c = 0; c < 4; ++c) acc[r][c] = 0.f;
#pragma unroll 4
    for (int i = 0; i < 128; ++i) {
      const float4 w = *reinterpret_cast<const float4*>(Wo2 + (size_t)i * 128 + c0);
#pragma unroll
      for (int r = 0; r < 4; ++r) {
        float v = sbuf1[(rb + r) * 128 + i];
        acc[r][0] = fmaf(v, w.x, acc[r][0]);
        acc[r][1] = fmaf(v, w.y, acc[r][1]);
        acc[r][2] = fmaf(v, w.z, acc[r][2]);
        acc[r][3] = fmaf(v, w.w, acc[r][3]);
      }
    }
    const float4 bv = *reinterpret_cast<const float4*>(bo2 + c0);
#pragma unroll
    for (int r = 0; r < 4; ++r) {
      float4 o;
      o.x = fmaxf(acc[r][0] + bv.x, 0.f);
      o.y = fmaxf(acc[r][1] + bv.y, 0.f);
      o.z = fmaxf(acc[r][2] + bv.z, 0.f);
      o.w = fmaxf(acc[r][3] + bv.w, 0.f);
      *reinterpret_cast<float4*>(sbuf2 + (rb + r) * 128 + c0) = o;
    }
  }
  __syncthreads();
  {
    const int c2 = (tid & 31) * 2;
    float acc[4][2];
#pragma unroll
    for (int r = 0; r < 4; ++r) { acc[r][0] = 0.f; acc[r][1] = 0.f; }
#pragma unroll 4
    for (int i = 0; i < 128; ++i) {
      const float2 w = *reinterpret_cast<const float2*>(Wo3 + (size_t)i * 64 + c2);
#pragma unroll
      for (int r = 0; r < 4; ++r) {
        float v = sbuf2[(rb + r) * 128 + i];
        acc[r][0] = fmaf(v, w.x, acc[r][0]);
        acc[r][1] = fmaf(v, w.y, acc[r][1]);
      }
    }
    const float2 bv = *reinterpret_cast<const float2*>(bo3 + c2);
#pragma unroll
    for (int r = 0; r < 4; ++r) {
      float2 o;
      o.x = acc[r][0] + bv.x;
      o.y = acc[r][1] + bv.y;
      *reinterpret_cast<float2*>(out + (size_t)(b0 + rb + r) * 64 + c2) = o;
    }
  }
}

// ---------------------------------------------------------------------------
extern "C" void kernel_launch(void* const* d_in, const int* in_sizes, int n_in,
                              void* d_out, int out_size, void* d_ws, size_t ws_size,
                              hipStream_t stream) {
  const float* x      = (const float*)d_in[0];
  const int*   ei     = (const int*)d_in[1];
  const float* ea     = (const float*)d_in[2];
  const float* gfeat  = (const float*)d_in[3];
  const float* W1_rel = (const float*)d_in[5];
  const float* b1     = (const float*)d_in[6];
  const float* W1_root= (const float*)d_in[7];
  const float* W2_rel = (const float*)d_in[8];
  const float* b2     = (const float*)d_in[9];
  const float* W2_root= (const float*)d_in[10];
  const float* Wg1 = (const float*)d_in[11];
  const float* bg1 = (const float*)d_in[12];
  const float* Wg2 = (const float*)d_in[13];
  const float* bg2 = (const float*)d_in[14];
  const float* Wg3 = (const float*)d_in[15];
  const float* bg3 = (const float*)d_in[16];
  const float* Wo1 = (const float*)d_in[17];
  const float* bo1 = (const float*)d_in[18];
  const float* Wo2 = (const float*)d_in[19];
  const float* bo2 = (const float*)d_in[20];
  const float* Wo3 = (const float*)d_in[21];
  const float* bo3 = (const float*)d_in[22];
  float* outp = (float*)d_out;

  // ---- write-routed layout (~420 MB) ----
  float*    msg1    = (float*)d_ws;                       // NE*16 f (302 MB)
  float*    msg2    = msg1;                               // overlays (NE*4 f)
  float*    embeds  = msg1 + (size_t)NE * 4;              // overlays dead msg1 tail
  uint2*    rec     = (uint2*)(msg1 + (size_t)NE * 16);   // 37.7 MB
  unsigned* slotmap = (unsigned*)(rec + NE);              // 18.9 MB
  unsigned char* dlo = (unsigned char*)(slotmap + NE);    // 4.7 MB
  float*    z2      = (float*)(dlo + NE);                 // 28.3 MB
  float*    r2      = z2 + (size_t)NN * 4;                // 28.3 MB
  unsigned* hist_s  = (unsigned*)(r2 + (size_t)NN * 4);   // NBK
  unsigned* hist_d  = hist_s + NBK;                       // NBK
  unsigned* sbase   = hist_d + NBK;                       // NBK+1
  unsigned* scur    = sbase + NBK + 1;                    // NBK
  unsigned* dbase   = scur + NBK;                         // NBK+1
  unsigned* dcur    = dbase + NBK + 1;                    // NBK
  size_t req = (size_t)((char*)(dcur + NBK) - (char*)d_ws);

  if (ws_size >= req) {
    hipMemsetAsync(hist_s, 0, 2 * NBK * sizeof(unsigned), stream);
    k_histAB   <<<NE / 256, 256, 0, stream>>>(ei, hist_s, hist_d);
    k_scan     <<<1, 1024, 0, stream>>>(hist_s, sbase, scur);
    k_scan     <<<1, 1024, 0, stream>>>(hist_d, dbase, dcur);
    k_place_src<<<NE / 256, 256, 0, stream>>>(ei, ea, scur, rec);
    k_msg1     <<<NBK, 256, 0, stream>>>(rec, sbase, x, dcur,
                                         (float4*)msg1, dlo, slotmap);
    k_conv1agg <<<NBK, 256, 0, stream>>>((const float4*)msg1, dlo, dbase, x,
                                         W1_rel, b1, W1_root,
                                         W2_rel, b2, W2_root, z2, r2);
    k_msg2     <<<NBK, 256, 0, stream>>>(rec, sbase, z2, slotmap, (float4*)msg2);
    k_conv2agg <<<NBK, 256, 0, stream>>>((const float4*)msg2, dlo, dbase, r2,
                                         embeds);
    k_final    <<<BD / TB, 256, 0, stream>>>(embeds, gfeat,
                                             Wg1, bg1, Wg2, bg2, Wg3, bg3,
                                             Wo1, bo1, Wo2, bo2, Wo3, bo3, outp);
  } else {
    // fallback: round-8 pipeline (~123 MB)
    uint2*    frec   = (uint2*)d_ws;
    float*    fz2    = (float*)(frec + NE);
    float*    fr2    = fz2 + (size_t)NN * 4;
    float*    femb   = fr2 + (size_t)NN * 4;
    unsigned* fhist  = (unsigned*)(femb + (size_t)NN * 4);
    unsigned* fbase  = fhist + NBK;
    unsigned* fcur   = fbase + NBK + 1;

    hipMemsetAsync(fhist, 0, NBK * sizeof(unsigned), stream);
    k_histAB<<<NE / 256, 256, 0, stream>>>(ei, fhist, fhist);  // only dst used
    k_scan <<<1, 1024, 0, stream>>>(fhist, fbase, fcur);
    k_place<<<NE / 256, 256, 0, stream>>>(ei, ea, fcur, frec);
    for (unsigned q = 0; q < 4; ++q)
      k_conv1<<<QBK, 256, 0, stream>>>(frec, fbase, x, W1_rel, b1, W1_root,
                                       W2_rel, b2, W2_root, fz2, fr2, q * QBK);
    k_conv2<<<NBK2, 256, 0, stream>>>(frec, fbase, fz2, fr2, femb);
    k_final<<<BD / TB, 256, 0, stream>>>(femb, gfeat,
                                         Wg1, bg1, Wg2, bg2, Wg3, bg3,
                                         Wo1, bo1, Wo2, bo2, Wo3, bo3, outp);
  }
}

// Round 11
// 772.915 us; speedup vs baseline: 2.2997x; 2.1085x over previous
//
#include <hip/hip_runtime.h>

// Problem constants
#define BD   32768
#define NPG  54
#define NN   (BD * NPG)          // 1,769,472 nodes
#define NE   (BD * 144)          // 4,718,592 edges
#define DIN  16
#define DH   32
#define GLOBF 16
#define TB   32
#define RB   256                 // nodes per dst bucket
#define NBK  (NN / RB)           // 6912 buckets
#define QBK  (NBK / 4)           // conv1 quarter dispatches (profiling visibility)
#define SRCM 0x1FFFFFu           // 21-bit src mask
#define CH   512                 // messages per sort-chunk
#define STW  20                  // conv1 sort-row stride (floats): 80B -> 16B-aligned, 8 bank groups
#define ST2  4                   // conv2 sort-row stride (floats): 16B-aligned, 8 bank groups

// ---------------------------------------------------------------------------
// Pass 1: histogram of dst buckets
// ---------------------------------------------------------------------------
__global__ __launch_bounds__(256) void k_hist(const int* __restrict__ ei,
                                              unsigned* __restrict__ hist) {
  unsigned e = blockIdx.x * 256u + threadIdx.x;
  unsigned d = (unsigned)ei[NE + e];
  atomicAdd(&hist[d >> 8], 1u);
}

// ---------------------------------------------------------------------------
// Pass 2: exclusive scan of 6912 bucket counts (single block)
// ---------------------------------------------------------------------------
__global__ __launch_bounds__(1024) void k_scan(const unsigned* __restrict__ hist,
                                               unsigned* __restrict__ base,
                                               unsigned* __restrict__ cursor) {
  __shared__ unsigned s[1024];
  const int tid = threadIdx.x;
  unsigned loc[7]; unsigned run = 0;
#pragma unroll
  for (int j = 0; j < 7; ++j) {
    int idx = tid * 7 + j;
    unsigned v = (idx < NBK) ? hist[idx] : 0u;
    loc[j] = run; run += v;
  }
  s[tid] = run; __syncthreads();
  for (int off = 1; off < 1024; off <<= 1) {
    unsigned t = (tid >= off) ? s[tid - off] : 0u;
    __syncthreads(); s[tid] += t; __syncthreads();
  }
  unsigned cb = tid ? s[tid - 1] : 0u;
#pragma unroll
  for (int j = 0; j < 7; ++j) {
    int idx = tid * 7 + j;
    if (idx < NBK) { unsigned b = cb + loc[j]; base[idx] = b; cursor[idx] = b; }
  }
  if (tid == 1023) base[NBK] = s[1023];
}

// ---------------------------------------------------------------------------
// Pass 3: place edge records dst-bucket-sorted: {src:21 | dlo:8 <<21, w}
// ---------------------------------------------------------------------------
__global__ __launch_bounds__(256) void k_place(const int* __restrict__ ei,
                                               const float* __restrict__ ea,
                                               unsigned* __restrict__ cursor,
                                               uint2* __restrict__ rec) {
  unsigned e = blockIdx.x * 256u + threadIdx.x;
  unsigned s = (unsigned)ei[e];
  unsigned d = (unsigned)ei[NE + e];
  float w = ea[e];
  unsigned pos = atomicAdd(&cursor[d >> 8], 1u);
  rec[pos] = make_uint2(s | ((d & 255u) << 21), __float_as_uint(w));
}

// ---------------------------------------------------------------------------
// Conv1 (sort-based): per dst bucket, chunks of CH messages:
//   gather 2 rows/thread -> rank (1 LDS atomic) -> block scan -> scatter
//   (ds_write_b128, sorted by node) -> per-node contiguous sum.
// Then fused node transform -> z2, r2.  16x fewer LDS atomics than LDS-atomic tile.
// ---------------------------------------------------------------------------
__global__ __launch_bounds__(256) void k_conv1s(
    const uint2* __restrict__ rec, const unsigned* __restrict__ base,
    const float* __restrict__ x,
    const float* __restrict__ W1_rel, const float* __restrict__ b1,
    const float* __restrict__ W1_root,
    const float* __restrict__ W2_rel, const float* __restrict__ b2,
    const float* __restrict__ W2_root,
    float* __restrict__ z2, float* __restrict__ r2, unsigned bkoff) {
  __shared__ float buf[CH * STW];        // 40960 B sorted message rows
  __shared__ unsigned hist[256];         // per-node counts
  __shared__ unsigned sc[256];           // scan / offset table
  const int tid = threadIdx.x;
  const unsigned bk = blockIdx.x + bkoff;
  const unsigned r0 = base[bk], r1 = base[bk + 1];

  float a[16];
#pragma unroll
  for (int i = 0; i < 16; ++i) a[i] = 0.f;

  for (unsigned c0 = r0; c0 < r1; c0 += CH) {
    hist[tid] = 0u;
    __syncthreads();

    const unsigned i0 = c0 + tid;
    const unsigned i1 = c0 + 256u + tid;
    const bool qa = i0 < r1;
    const bool qb = i1 < r1;
    float4 xa0, xa1, xa2, xa3, xb0, xb1, xb2, xb3;
    unsigned la = 0, lb = 0; float wa = 0.f, wb = 0.f;
    unsigned rka = 0, rkb = 0;
    if (qa) {
      uint2 ra = rec[i0];
      const float4* xp = reinterpret_cast<const float4*>(x + (size_t)(ra.x & SRCM) * 16);
      xa0 = xp[0]; xa1 = xp[1]; xa2 = xp[2]; xa3 = xp[3];
      la = ra.x >> 21; wa = __uint_as_float(ra.y);
    }
    if (qb) {
      uint2 rb = rec[i1];
      const float4* xp = reinterpret_cast<const float4*>(x + (size_t)(rb.x & SRCM) * 16);
      xb0 = xp[0]; xb1 = xp[1]; xb2 = xp[2]; xb3 = xp[3];
      lb = rb.x >> 21; wb = __uint_as_float(rb.y);
    }
    if (qa) rka = atomicAdd(&hist[la], 1u);   // single LDS atomic per message
    if (qb) rkb = atomicAdd(&hist[lb], 1u);
    __syncthreads();

    // 256-wide inclusive scan of counts -> exclusive offsets in sc[]
    const unsigned cnt = hist[tid];
    sc[tid] = cnt; __syncthreads();
    for (int off = 1; off < 256; off <<= 1) {
      unsigned t = (tid >= off) ? sc[tid - off] : 0u;
      __syncthreads(); sc[tid] += t; __syncthreads();
    }
    const unsigned myoff = sc[tid] - cnt;
    __syncthreads();
    sc[tid] = myoff;                       // publish exclusive offsets
    __syncthreads();

    if (qa) {
      float* bp = buf + (size_t)(sc[la] + rka) * STW;
      reinterpret_cast<float4*>(bp)[0] = make_float4(xa0.x*wa, xa0.y*wa, xa0.z*wa, xa0.w*wa);
      reinterpret_cast<float4*>(bp)[1] = make_float4(xa1.x*wa, xa1.y*wa, xa1.z*wa, xa1.w*wa);
      reinterpret_cast<float4*>(bp)[2] = make_float4(xa2.x*wa, xa2.y*wa, xa2.z*wa, xa2.w*wa);
      reinterpret_cast<float4*>(bp)[3] = make_float4(xa3.x*wa, xa3.y*wa, xa3.z*wa, xa3.w*wa);
    }
    if (qb) {
      float* bp = buf + (size_t)(sc[lb] + rkb) * STW;
      reinterpret_cast<float4*>(bp)[0] = make_float4(xb0.x*wb, xb0.y*wb, xb0.z*wb, xb0.w*wb);
      reinterpret_cast<float4*>(bp)[1] = make_float4(xb1.x*wb, xb1.y*wb, xb1.z*wb, xb1.w*wb);
      reinterpret_cast<float4*>(bp)[2] = make_float4(xb2.x*wb, xb2.y*wb, xb2.z*wb, xb2.w*wb);
      reinterpret_cast<float4*>(bp)[3] = make_float4(xb3.x*wb, xb3.y*wb, xb3.z*wb, xb3.w*wb);
    }
    __syncthreads();

    // per-node contiguous sum (thread tid owns node tid of this bucket)
    for (unsigned k = 0; k < cnt; ++k) {
      const float* bp = buf + (size_t)(myoff + k) * STW;
      float4 m0 = reinterpret_cast<const float4*>(bp)[0];
      float4 m1 = reinterpret_cast<const float4*>(bp)[1];
      float4 m2 = reinterpret_cast<const float4*>(bp)[2];
      float4 m3 = reinterpret_cast<const float4*>(bp)[3];
      a[0]  += m0.x; a[1]  += m0.y; a[2]  += m0.z; a[3]  += m0.w;
      a[4]  += m1.x; a[5]  += m1.y; a[6]  += m1.z; a[7]  += m1.w;
      a[8]  += m2.x; a[9]  += m2.y; a[10] += m2.z; a[11] += m2.w;
      a[12] += m3.x; a[13] += m3.y; a[14] += m3.z; a[15] += m3.w;
    }
    __syncthreads();                       // buf/hist reusable next chunk
  }

  // fused node transform: node n = bk*RB + tid
  size_t n = (size_t)bk * RB + tid;
  float xv[16];
  {
    const float4* xp = reinterpret_cast<const float4*>(x + n * 16);
#pragma unroll
    for (int q = 0; q < 4; ++q) {
      float4 t2 = xp[q];
      xv[4*q+0] = t2.x; xv[4*q+1] = t2.y; xv[4*q+2] = t2.z; xv[4*q+3] = t2.w;
    }
  }
  float h[DH];
#pragma unroll
  for (int j = 0; j < DH; ++j) h[j] = b1[j];
#pragma unroll
  for (int i = 0; i < DIN; ++i) {
    float ai = a[i], xi = xv[i];
#pragma unroll
    for (int j = 0; j < DH; ++j)
      h[j] = fmaf(ai, W1_rel[i * DH + j], fmaf(xi, W1_root[i * DH + j], h[j]));
  }
#pragma unroll
  for (int j = 0; j < DH; ++j) h[j] = fmaxf(h[j], 0.f);
  float z[4] = {0.f, 0.f, 0.f, 0.f};
  float r[4] = {b2[0], b2[1], b2[2], b2[3]};
#pragma unroll
  for (int j = 0; j < DH; ++j) {
    float hj = h[j];
#pragma unroll
    for (int k = 0; k < 4; ++k) {
      z[k] = fmaf(hj, W2_rel[j * 4 + k], z[k]);
      r[k] = fmaf(hj, W2_root[j * 4 + k], r[k]);
    }
  }
  *reinterpret_cast<float4*>(z2 + n * 4) = make_float4(z[0], z[1], z[2], z[3]);
  *reinterpret_cast<float4*>(r2 + n * 4) = make_float4(r[0], r[1], r[2], r[3]);
}

// ---------------------------------------------------------------------------
// Conv2 (sort-based): same skeleton, 16B rows; embeds = relu(sum + r2)
// ---------------------------------------------------------------------------
__global__ __launch_bounds__(256) void k_conv2s(
    const uint2* __restrict__ rec, const unsigned* __restrict__ base,
    const float* __restrict__ z2, const float* __restrict__ r2,
    float* __restrict__ embeds) {
  __shared__ float buf[CH * ST2];        // 8192 B
  __shared__ unsigned hist[256];
  __shared__ unsigned sc[256];
  const int tid = threadIdx.x;
  const unsigned bk = blockIdx.x;
  const unsigned r0 = base[bk], r1 = base[bk + 1];

  float4 a = make_float4(0.f, 0.f, 0.f, 0.f);

  for (unsigned c0 = r0; c0 < r1; c0 += CH) {
    hist[tid] = 0u;
    __syncthreads();

    const unsigned i0 = c0 + tid;
    const unsigned i1 = c0 + 256u + tid;
    const bool qa = i0 < r1;
    const bool qb = i1 < r1;
    float4 za, zb;
    unsigned la = 0, lb = 0; float wa = 0.f, wb = 0.f;
    unsigned rka = 0, rkb = 0;
    if (qa) {
      uint2 ra = rec[i0];
      za = *reinterpret_cast<const float4*>(z2 + (size_t)(ra.x & SRCM) * 4);
      la = ra.x >> 21; wa = __uint_as_float(ra.y);
    }
    if (qb) {
      uint2 rb = rec[i1];
      zb = *reinterpret_cast<const float4*>(z2 + (size_t)(rb.x & SRCM) * 4);
      lb = rb.x >> 21; wb = __uint_as_float(rb.y);
    }
    if (qa) rka = atomicAdd(&hist[la], 1u);
    if (qb) rkb = atomicAdd(&hist[lb], 1u);
    __syncthreads();

    const unsigned cnt = hist[tid];
    sc[tid] = cnt; __syncthreads();
    for (int off = 1; off < 256; off <<= 1) {
      unsigned t = (tid >= off) ? sc[tid - off] : 0u;
      __syncthreads(); sc[tid] += t; __syncthreads();
    }
    const unsigned myoff = sc[tid] - cnt;
    __syncthreads();
    sc[tid] = myoff;
    __syncthreads();

    if (qa)
      *reinterpret_cast<float4*>(buf + (size_t)(sc[la] + rka) * ST2) =
          make_float4(za.x*wa, za.y*wa, za.z*wa, za.w*wa);
    if (qb)
      *reinterpret_cast<float4*>(buf + (size_t)(sc[lb] + rkb) * ST2) =
          make_float4(zb.x*wb, zb.y*wb, zb.z*wb, zb.w*wb);
    __syncthreads();

    for (unsigned k = 0; k < cnt; ++k) {
      float4 m = *reinterpret_cast<const float4*>(buf + (size_t)(myoff + k) * ST2);
      a.x += m.x; a.y += m.y; a.z += m.z; a.w += m.w;
    }
    __syncthreads();
  }

  size_t n = (size_t)bk * RB + tid;
  const float4 rr = *reinterpret_cast<const float4*>(r2 + n * 4);
  float4 o;
  o.x = fmaxf(a.x + rr.x, 0.f);
  o.y = fmaxf(a.y + rr.y, 0.f);
  o.z = fmaxf(a.z + rr.z, 0.f);
  o.w = fmaxf(a.w + rr.w, 0.f);
  *reinterpret_cast<float4*>(embeds + n * 4) = o;
}

// ---------------------------------------------------------------------------
// Final MLP
// ---------------------------------------------------------------------------
__global__ __launch_bounds__(256) void k_final(
    const float* __restrict__ embeds, const float* __restrict__ gfeat,
    const float* __restrict__ Wg1, const float* __restrict__ bg1,
    const float* __restrict__ Wg2, const float* __restrict__ bg2,
    const float* __restrict__ Wg3, const float* __restrict__ bg3,
    const float* __restrict__ Wo1, const float* __restrict__ bo1,
    const float* __restrict__ Wo2, const float* __restrict__ bo2,
    const float* __restrict__ Wo3, const float* __restrict__ bo3,
    float* __restrict__ out) {
  __shared__ float smem[TB * 232 + TB * 128];
  float* svec  = smem;
  float* sbuf1 = smem + TB * 232;
  float* sbuf2 = smem;
  const int tid = threadIdx.x;
  const int b0  = blockIdx.x * TB;
  {
    const size_t gbase = (size_t)b0 * 216;
    for (int idx = tid; idx < TB * 216; idx += 256) {
      int b = idx / 216;
      int k = idx - b * 216;
      svec[b * 232 + k] = embeds[gbase + idx];
    }
  }
  if (tid < TB) {
    const float* gf = gfeat + (size_t)(b0 + tid) * GLOBF;
    float gin[16];
#pragma unroll
    for (int i = 0; i < 16; ++i) gin[i] = gf[i];
    float g1[8];
#pragma unroll
    for (int j = 0; j < 8; ++j) {
      float acc = bg1[j];
#pragma unroll
      for (int i = 0; i < 16; ++i) acc = fmaf(gin[i], Wg1[i * 8 + j], acc);
      g1[j] = fmaxf(acc, 0.f);
    }
    float g2[8];
#pragma unroll
    for (int j = 0; j < 8; ++j) {
      float acc = bg2[j];
#pragma unroll
      for (int i = 0; i < 8; ++i) acc = fmaf(g1[i], Wg2[i * 8 + j], acc);
      g2[j] = fmaxf(acc, 0.f);
    }
#pragma unroll
    for (int j = 0; j < 16; ++j) {
      float acc = bg3[j];
#pragma unroll
      for (int i = 0; i < 8; ++i) acc = fmaf(g2[i], Wg3[i * 16 + j], acc);
      svec[tid * 232 + 216 + j] = fmaxf(acc, 0.f);
    }
  }
  __syncthreads();
  const int c0 = (tid & 31) * 4;
  const int rb = (tid >> 5) * 4;
  {
    float acc[4][4];
#pragma unroll
    for (int r = 0; r < 4; ++r)
#pragma unroll
      for (int c = 0; c < 4; ++c) acc[r][c] = 0.f;
#pragma unroll 4
    for (int i = 0; i < 232; ++i) {
      const float4 w = *reinterpret_cast<const float4*>(Wo1 + (size_t)i * 128 + c0);
#pragma unroll
      for (int r = 0; r < 4; ++r) {
        float v = svec[(rb + r) * 232 + i];
        acc[r][0] = fmaf(v, w.x, acc[r][0]);
        acc[r][1] = fmaf(v, w.y, acc[r][1]);
        acc[r][2] = fmaf(v, w.z, acc[r][2]);
        acc[r][3] = fmaf(v, w.w, acc[r][3]);
      }
    }
    const float4 bv = *reinterpret_cast<const float4*>(bo1 + c0);
#pragma unroll
    for (int r = 0; r < 4; ++r) {
      float4 o;
      o.x = fmaxf(acc[r][0] + bv.x, 0.f);
      o.y = fmaxf(acc[r][1] + bv.y, 0.f);
      o.z = fmaxf(acc[r][2] + bv.z, 0.f);
      o.w = fmaxf(acc[r][3] + bv.w, 0.f);
      *reinterpret_cast<float4*>(sbuf1 + (rb + r) * 128 + c0) = o;
    }
  }
  __syncthreads();
  {
    float acc[4][4];
#pragma unroll
    for (int r = 0; r < 4; ++r)
#pragma unroll
      for (int c = 0; c < 4; ++c) acc[r][c] = 0.f;
#pragma unroll 4
    for (int i = 0; i < 128; ++i) {
      const float4 w = *reinterpret_cast<const float4*>(Wo2 + (size_t)i * 128 + c0);
#pragma unroll
      for (int r = 0; r < 4; ++r) {
        float v = sbuf1[(rb + r) * 128 + i];
        acc[r][0] = fmaf(v, w.x, acc[r][0]);
        acc[r][1] = fmaf(v, w.y, acc[r][1]);
        acc[r][2] = fmaf(v, w.z, acc[r][2]);
        acc[r][3] = fmaf(v, w.w, acc[r][3]);
      }
    }
    const float4 bv = *reinterpret_cast<const float4*>(bo2 + c0);
#pragma unroll
    for (int r = 0; r < 4; ++r) {
      float4 o;
      o.x = fmaxf(acc[r][0] + bv.x, 0.f);
      o.y = fmaxf(acc[r][1] + bv.y, 0.f);
      o.z = fmaxf(acc[r][2] + bv.z, 0.f);
      o.w = fmaxf(acc[r][3] + bv.w, 0.f);
      *reinterpret_cast<float4*>(sbuf2 + (rb + r) * 128 + c0) = o;
    }
  }
  __syncthreads();
  {
    const int c2 = (tid & 31) * 2;
    float acc[4][2];
#pragma unroll
    for (int r = 0; r < 4; ++r) { acc[r][0] = 0.f; acc[r][1] = 0.f; }
#pragma unroll 4
    for (int i = 0; i < 128; ++i) {
      const float2 w = *reinterpret_cast<const float2*>(Wo3 + (size_t)i * 64 + c2);
#pragma unroll
      for (int r = 0; r < 4; ++r) {
        float v = sbuf2[(rb + r) * 128 + i];
        acc[r][0] = fmaf(v, w.x, acc[r][0]);
        acc[r][1] = fmaf(v, w.y, acc[r][1]);
      }
    }
    const float2 bv = *reinterpret_cast<const float2*>(bo3 + c2);
#pragma unroll
    for (int r = 0; r < 4; ++r) {
      float2 o;
      o.x = acc[r][0] + bv.x;
      o.y = acc[r][1] + bv.y;
      *reinterpret_cast<float2*>(out + (size_t)(b0 + rb + r) * 64 + c2) = o;
    }
  }
}

// ---------------------------------------------------------------------------
extern "C" void kernel_launch(void* const* d_in, const int* in_sizes, int n_in,
                              void* d_out, int out_size, void* d_ws, size_t ws_size,
                              hipStream_t stream) {
  const float* x      = (const float*)d_in[0];
  const int*   ei     = (const int*)d_in[1];
  const float* ea     = (const float*)d_in[2];
  const float* gfeat  = (const float*)d_in[3];
  const float* W1_rel = (const float*)d_in[5];
  const float* b1     = (const float*)d_in[6];
  const float* W1_root= (const float*)d_in[7];
  const float* W2_rel = (const float*)d_in[8];
  const float* b2     = (const float*)d_in[9];
  const float* W2_root= (const float*)d_in[10];
  const float* Wg1 = (const float*)d_in[11];
  const float* bg1 = (const float*)d_in[12];
  const float* Wg2 = (const float*)d_in[13];
  const float* bg2 = (const float*)d_in[14];
  const float* Wg3 = (const float*)d_in[15];
  const float* bg3 = (const float*)d_in[16];
  const float* Wo1 = (const float*)d_in[17];
  const float* bo1 = (const float*)d_in[18];
  const float* Wo2 = (const float*)d_in[19];
  const float* bo2 = (const float*)d_in[20];
  const float* Wo3 = (const float*)d_in[21];
  const float* bo3 = (const float*)d_in[22];
  float* outp = (float*)d_out;

  // workspace (~123 MB)
  uint2*    rec    = (uint2*)d_ws;                       // NE*8B
  float*    z2     = (float*)(rec + NE);                 // NN*4 f
  float*    r2     = z2 + (size_t)NN * 4;                // NN*4 f
  float*    embeds = r2 + (size_t)NN * 4;                // NN*4 f
  unsigned* hist   = (unsigned*)(embeds + (size_t)NN * 4); // NBK
  unsigned* base   = hist + NBK;                         // NBK+1
  unsigned* cursor = base + NBK + 1;                     // NBK

  hipMemsetAsync(hist, 0, NBK * sizeof(unsigned), stream);
  k_hist <<<NE / 256, 256, 0, stream>>>(ei, hist);
  k_scan <<<1, 1024, 0, stream>>>(hist, base, cursor);
  k_place<<<NE / 256, 256, 0, stream>>>(ei, ea, cursor, rec);
  for (unsigned q = 0; q < 4; ++q)
    k_conv1s<<<QBK, 256, 0, stream>>>(rec, base, x, W1_rel, b1, W1_root,
                                      W2_rel, b2, W2_root, z2, r2, q * QBK);
  k_conv2s<<<NBK, 256, 0, stream>>>(rec, base, z2, r2, embeds);
  k_final<<<BD / TB, 256, 0, stream>>>(embeds, gfeat,
                                       Wg1, bg1, Wg2, bg2, Wg3, bg3,
                                       Wo1, bo1, Wo2, bo2, Wo3, bo3, outp);
}

// Round 12
// 654.063 us; speedup vs baseline: 2.7176x; 1.1817x over previous
//
#include <hip/hip_runtime.h>

// Problem constants
#define BD   32768
#define NPG  54
#define NN   (BD * NPG)          // 1,769,472 nodes
#define NE   (BD * 144)          // 4,718,592 edges
#define DIN  16
#define DH   32
#define GLOBF 16
#define TB   32
#define RB   256                 // nodes per dst bucket
#define NBK  (NN / RB)           // 6912 buckets
#define QBK  (NBK / 4)           // quarter dispatches (profiling visibility)
#define QE   (NE / 4)            // quarter edge range for place
#define SRCM 0x1FFFFFu           // 21-bit src mask
#define CH   512                 // messages per sort-chunk
#define STW  20                  // conv1 sort-row stride (floats)
#define ST2  4                   // conv2 sort-row stride (floats)
#define HB   256                 // hist blocks

// ---------------------------------------------------------------------------
// Pass 1: histogram of dst buckets (LDS-staged: 1 flush per block)
// ---------------------------------------------------------------------------
__global__ __launch_bounds__(256) void k_histl(const int* __restrict__ ei,
                                               unsigned* __restrict__ hist) {
  __shared__ unsigned h[NBK];                            // 27648 B
  const int tid = threadIdx.x;
  for (int i = tid; i < NBK; i += 256) h[i] = 0u;
  __syncthreads();
  const unsigned base = blockIdx.x * (NE / HB);
  for (unsigned i = tid; i < NE / HB; i += 256u) {
    unsigned d = (unsigned)ei[NE + base + i];
    atomicAdd(&h[d >> 8], 1u);
  }
  __syncthreads();
  for (int i = tid; i < NBK; i += 256)
    if (h[i]) atomicAdd(&hist[i], h[i]);
}

// ---------------------------------------------------------------------------
// Pass 2: exclusive scan of 6912 bucket counts (single block)
// ---------------------------------------------------------------------------
__global__ __launch_bounds__(1024) void k_scan(const unsigned* __restrict__ hist,
                                               unsigned* __restrict__ base,
                                               unsigned* __restrict__ cursor) {
  __shared__ unsigned s[1024];
  const int tid = threadIdx.x;
  unsigned loc[7]; unsigned run = 0;
#pragma unroll
  for (int j = 0; j < 7; ++j) {
    int idx = tid * 7 + j;
    unsigned v = (idx < NBK) ? hist[idx] : 0u;
    loc[j] = run; run += v;
  }
  s[tid] = run; __syncthreads();
  for (int off = 1; off < 1024; off <<= 1) {
    unsigned t = (tid >= off) ? s[tid - off] : 0u;
    __syncthreads(); s[tid] += t; __syncthreads();
  }
  unsigned cb = tid ? s[tid - 1] : 0u;
#pragma unroll
  for (int j = 0; j < 7; ++j) {
    int idx = tid * 7 + j;
    if (idx < NBK) { unsigned b = cb + loc[j]; base[idx] = b; cursor[idx] = b; }
  }
  if (tid == 1023) base[NBK] = s[1023];
}

// ---------------------------------------------------------------------------
// Pass 3: place records dst-bucket-sorted: {src:21 | dlo:8 <<21, w}
// (quartered over edge ranges; cursor state carries across launches)
// ---------------------------------------------------------------------------
__global__ __launch_bounds__(256) void k_place(const int* __restrict__ ei,
                                               const float* __restrict__ ea,
                                               unsigned* __restrict__ cursor,
                                               uint2* __restrict__ rec,
                                               unsigned e0) {
  unsigned e = e0 + blockIdx.x * 256u + threadIdx.x;
  unsigned s = (unsigned)ei[e];
  unsigned d = (unsigned)ei[NE + e];
  float w = ea[e];
  unsigned pos = atomicAdd(&cursor[d >> 8], 1u);
  rec[pos] = make_uint2(s | ((d & 255u) << 21), __float_as_uint(w));
}

// ---------------------------------------------------------------------------
// Conv1 (dual counting sort): per chunk of CH records:
//  rank by dst-lo (aggregation order) AND by src-coarse (gather order) via one
//  packed 16+16 scan; gather x in ascending-src order (cross-block temporal
//  locality -> L2/L3 captures the 2.67x line reuse); scatter to dst-sorted
//  LDS rows; per-node contiguous sum.  Then fused node transform -> z2, r2.
// ---------------------------------------------------------------------------
__global__ __launch_bounds__(256) void k_conv1s(
    const uint2* __restrict__ rec, const unsigned* __restrict__ base,
    const float* __restrict__ x,
    const float* __restrict__ W1_rel, const float* __restrict__ b1,
    const float* __restrict__ W1_root,
    const float* __restrict__ W2_rel, const float* __restrict__ b2,
    const float* __restrict__ W2_root,
    float* __restrict__ z2, float* __restrict__ r2, unsigned bkoff) {
  __shared__ float buf[CH * STW];        // 40960 B sorted message rows
  __shared__ uint2 prm[CH];              // 4096 B src-sorted permutation
  __shared__ unsigned hd[256];           // per-node (dst-lo) counts
  __shared__ unsigned hs[256];           // per-src-coarse counts
  __shared__ unsigned sc[256];           // packed scan
  const int tid = threadIdx.x;
  const unsigned bk = blockIdx.x + bkoff;
  const unsigned r0 = base[bk], r1 = base[bk + 1];

  float a[16];
#pragma unroll
  for (int i = 0; i < 16; ++i) a[i] = 0.f;

  for (unsigned c0 = r0; c0 < r1; c0 += CH) {
    const unsigned validCnt = min((unsigned)CH, r1 - c0);
    hd[tid] = 0u; hs[tid] = 0u;
    __syncthreads();

    // rank phase: 2 records/thread, dst-rank + src-rank
    const unsigned i0 = c0 + tid;
    const unsigned i1 = c0 + 256u + tid;
    const bool qa = i0 < r1;
    const bool qb = i1 < r1;
    unsigned srcA = 0, srcB = 0, la = 0, lb = 0, sa = 0, sb = 0;
    unsigned wa = 0, wb = 0, rkda = 0, rkdb = 0, rksa = 0, rksb = 0;
    if (qa) {
      uint2 ra = rec[i0];
      srcA = ra.x & SRCM; la = ra.x >> 21; sa = srcA >> 13; wa = ra.y;
    }
    if (qb) {
      uint2 rb = rec[i1];
      srcB = rb.x & SRCM; lb = rb.x >> 21; sb = srcB >> 13; wb = rb.y;
    }
    if (qa) { rkda = atomicAdd(&hd[la], 1u); rksa = atomicAdd(&hs[sa], 1u); }
    if (qb) { rkdb = atomicAdd(&hd[lb], 1u); rksb = atomicAdd(&hs[sb], 1u); }
    __syncthreads();

    // one packed scan: low 16 = dst counts, high 16 = src counts
    const unsigned cd = hd[tid];
    const unsigned packed = cd | (hs[tid] << 16);
    sc[tid] = packed; __syncthreads();
    for (int off = 1; off < 256; off <<= 1) {
      unsigned t = (tid >= off) ? sc[tid - off] : 0u;
      __syncthreads(); sc[tid] += t; __syncthreads();
    }
    const unsigned exclP = sc[tid] - packed;             // fields independent
    const unsigned myoff = exclP & 0xffffu;              // dst exclusive offset
    __syncthreads();
    sc[tid] = exclP;                                     // publish
    __syncthreads();

    if (qa) {
      unsigned dslot = (sc[la] & 0xffffu) + rkda;        // 0..511 (9 bits)
      unsigned spos  = (sc[sa] >> 16) + rksa;
      prm[spos] = make_uint2(srcA | (dslot << 21), wa);
    }
    if (qb) {
      unsigned dslot = (sc[lb] & 0xffffu) + rkdb;
      unsigned spos  = (sc[sb] >> 16) + rksb;
      prm[spos] = make_uint2(srcB | (dslot << 21), wb);
    }
    __syncthreads();

    // gather phase in ascending-src order
    {
      const bool ga = tid < validCnt;
      const bool gb = tid + 256u < validCnt;
      uint2 pa, pb;
      float4 xa0, xa1, xa2, xa3, xb0, xb1, xb2, xb3;
      if (ga) {
        pa = prm[tid];
        const float4* xp = reinterpret_cast<const float4*>(x + (size_t)(pa.x & SRCM) * 16);
        xa0 = xp[0]; xa1 = xp[1]; xa2 = xp[2]; xa3 = xp[3];
      }
      if (gb) {
        pb = prm[tid + 256];
        const float4* xp = reinterpret_cast<const float4*>(x + (size_t)(pb.x & SRCM) * 16);
        xb0 = xp[0]; xb1 = xp[1]; xb2 = xp[2]; xb3 = xp[3];
      }
      if (ga) {
        float w = __uint_as_float(pa.y);
        float* bp = buf + (size_t)(pa.x >> 21) * STW;
        reinterpret_cast<float4*>(bp)[0] = make_float4(xa0.x*w, xa0.y*w, xa0.z*w, xa0.w*w);
        reinterpret_cast<float4*>(bp)[1] = make_float4(xa1.x*w, xa1.y*w, xa1.z*w, xa1.w*w);
        reinterpret_cast<float4*>(bp)[2] = make_float4(xa2.x*w, xa2.y*w, xa2.z*w, xa2.w*w);
        reinterpret_cast<float4*>(bp)[3] = make_float4(xa3.x*w, xa3.y*w, xa3.z*w, xa3.w*w);
      }
      if (gb) {
        float w = __uint_as_float(pb.y);
        float* bp = buf + (size_t)(pb.x >> 21) * STW;
        reinterpret_cast<float4*>(bp)[0] = make_float4(xb0.x*w, xb0.y*w, xb0.z*w, xb0.w*w);
        reinterpret_cast<float4*>(bp)[1] = make_float4(xb1.x*w, xb1.y*w, xb1.z*w, xb1.w*w);
        reinterpret_cast<float4*>(bp)[2] = make_float4(xb2.x*w, xb2.y*w, xb2.z*w, xb2.w*w);
        reinterpret_cast<float4*>(bp)[3] = make_float4(xb3.x*w, xb3.y*w, xb3.z*w, xb3.w*w);
      }
    }
    __syncthreads();

    // per-node contiguous sum (thread tid owns node tid of this bucket)
    for (unsigned k = 0; k < cd; ++k) {
      const float* bp = buf + (size_t)(myoff + k) * STW;
      float4 m0 = reinterpret_cast<const float4*>(bp)[0];
      float4 m1 = reinterpret_cast<const float4*>(bp)[1];
      float4 m2 = reinterpret_cast<const float4*>(bp)[2];
      float4 m3 = reinterpret_cast<const float4*>(bp)[3];
      a[0]  += m0.x; a[1]  += m0.y; a[2]  += m0.z; a[3]  += m0.w;
      a[4]  += m1.x; a[5]  += m1.y; a[6]  += m1.z; a[7]  += m1.w;
      a[8]  += m2.x; a[9]  += m2.y; a[10] += m2.z; a[11] += m2.w;
      a[12] += m3.x; a[13] += m3.y; a[14] += m3.z; a[15] += m3.w;
    }
    __syncthreads();
  }

  // fused node transform: node n = bk*RB + tid
  size_t n = (size_t)bk * RB + tid;
  float xv[16];
  {
    const float4* xp = reinterpret_cast<const float4*>(x + n * 16);
#pragma unroll
    for (int q = 0; q < 4; ++q) {
      float4 t2 = xp[q];
      xv[4*q+0] = t2.x; xv[4*q+1] = t2.y; xv[4*q+2] = t2.z; xv[4*q+3] = t2.w;
    }
  }
  float h[DH];
#pragma unroll
  for (int j = 0; j < DH; ++j) h[j] = b1[j];
#pragma unroll
  for (int i = 0; i < DIN; ++i) {
    float ai = a[i], xi = xv[i];
#pragma unroll
    for (int j = 0; j < DH; ++j)
      h[j] = fmaf(ai, W1_rel[i * DH + j], fmaf(xi, W1_root[i * DH + j], h[j]));
  }
#pragma unroll
  for (int j = 0; j < DH; ++j) h[j] = fmaxf(h[j], 0.f);
  float z[4] = {0.f, 0.f, 0.f, 0.f};
  float r[4] = {b2[0], b2[1], b2[2], b2[3]};
#pragma unroll
  for (int j = 0; j < DH; ++j) {
    float hj = h[j];
#pragma unroll
    for (int k = 0; k < 4; ++k) {
      z[k] = fmaf(hj, W2_rel[j * 4 + k], z[k]);
      r[k] = fmaf(hj, W2_root[j * 4 + k], r[k]);
    }
  }
  *reinterpret_cast<float4*>(z2 + n * 4) = make_float4(z[0], z[1], z[2], z[3]);
  *reinterpret_cast<float4*>(r2 + n * 4) = make_float4(r[0], r[1], r[2], r[3]);
}

// ---------------------------------------------------------------------------
// Conv2 (dual counting sort, 16B rows): embeds = relu(sum + r2)
// ---------------------------------------------------------------------------
__global__ __launch_bounds__(256) void k_conv2s(
    const uint2* __restrict__ rec, const unsigned* __restrict__ base,
    const float* __restrict__ z2, const float* __restrict__ r2,
    float* __restrict__ embeds, unsigned bkoff) {
  __shared__ float buf[CH * ST2];        // 8192 B
  __shared__ uint2 prm[CH];              // 4096 B
  __shared__ unsigned hd[256];
  __shared__ unsigned hs[256];
  __shared__ unsigned sc[256];
  const int tid = threadIdx.x;
  const unsigned bk = blockIdx.x + bkoff;
  const unsigned r0 = base[bk], r1 = base[bk + 1];

  float4 a = make_float4(0.f, 0.f, 0.f, 0.f);
  unsigned myoffL = 0, cdL = 0;

  for (unsigned c0 = r0; c0 < r1; c0 += CH) {
    const unsigned validCnt = min((unsigned)CH, r1 - c0);
    hd[tid] = 0u; hs[tid] = 0u;
    __syncthreads();

    const unsigned i0 = c0 + tid;
    const unsigned i1 = c0 + 256u + tid;
    const bool qa = i0 < r1;
    const bool qb = i1 < r1;
    unsigned srcA = 0, srcB = 0, la = 0, lb = 0, sa = 0, sb = 0;
    unsigned wa = 0, wb = 0, rkda = 0, rkdb = 0, rksa = 0, rksb = 0;
    if (qa) {
      uint2 ra = rec[i0];
      srcA = ra.x & SRCM; la = ra.x >> 21; sa = srcA >> 13; wa = ra.y;
    }
    if (qb) {
      uint2 rb = rec[i1];
      srcB = rb.x & SRCM; lb = rb.x >> 21; sb = srcB >> 13; wb = rb.y;
    }
    if (qa) { rkda = atomicAdd(&hd[la], 1u); rksa = atomicAdd(&hs[sa], 1u); }
    if (qb) { rkdb = atomicAdd(&hd[lb], 1u); rksb = atomicAdd(&hs[sb], 1u); }
    __syncthreads();

    const unsigned cd = hd[tid];
    const unsigned packed = cd | (hs[tid] << 16);
    sc[tid] = packed; __syncthreads();
    for (int off = 1; off < 256; off <<= 1) {
      unsigned t = (tid >= off) ? sc[tid - off] : 0u;
      __syncthreads(); sc[tid] += t; __syncthreads();
    }
    const unsigned exclP = sc[tid] - packed;
    const unsigned myoff = exclP & 0xffffu;
    __syncthreads();
    sc[tid] = exclP;
    __syncthreads();

    if (qa) {
      unsigned dslot = (sc[la] & 0xffffu) + rkda;
      unsigned spos  = (sc[sa] >> 16) + rksa;
      prm[spos] = make_uint2(srcA | (dslot << 21), wa);
    }
    if (qb) {
      unsigned dslot = (sc[lb] & 0xffffu) + rkdb;
      unsigned spos  = (sc[sb] >> 16) + rksb;
      prm[spos] = make_uint2(srcB | (dslot << 21), wb);
    }
    __syncthreads();

    {
      const bool ga = tid < validCnt;
      const bool gb = tid + 256u < validCnt;
      uint2 pa, pb;
      float4 za, zb;
      if (ga) {
        pa = prm[tid];
        za = *reinterpret_cast<const float4*>(z2 + (size_t)(pa.x & SRCM) * 4);
      }
      if (gb) {
        pb = prm[tid + 256];
        zb = *reinterpret_cast<const float4*>(z2 + (size_t)(pb.x & SRCM) * 4);
      }
      if (ga) {
        float w = __uint_as_float(pa.y);
        *reinterpret_cast<float4*>(buf + (size_t)(pa.x >> 21) * ST2) =
            make_float4(za.x*w, za.y*w, za.z*w, za.w*w);
      }
      if (gb) {
        float w = __uint_as_float(pb.y);
        *reinterpret_cast<float4*>(buf + (size_t)(pb.x >> 21) * ST2) =
            make_float4(zb.x*w, zb.y*w, zb.z*w, zb.w*w);
      }
    }
    __syncthreads();

    for (unsigned k = 0; k < cd; ++k) {
      float4 m = *reinterpret_cast<const float4*>(buf + (size_t)(myoff + k) * ST2);
      a.x += m.x; a.y += m.y; a.z += m.z; a.w += m.w;
    }
    __syncthreads();
    myoffL = myoff; cdL = cd;                            // (quiet unused warnings)
  }
  (void)myoffL; (void)cdL;

  size_t n = (size_t)bk * RB + tid;
  const float4 rr = *reinterpret_cast<const float4*>(r2 + n * 4);
  float4 o;
  o.x = fmaxf(a.x + rr.x, 0.f);
  o.y = fmaxf(a.y + rr.y, 0.f);
  o.z = fmaxf(a.z + rr.z, 0.f);
  o.w = fmaxf(a.w + rr.w, 0.f);
  *reinterpret_cast<float4*>(embeds + n * 4) = o;
}

// ---------------------------------------------------------------------------
// Final MLP
// ---------------------------------------------------------------------------
__global__ __launch_bounds__(256) void k_final(
    const float* __restrict__ embeds, const float* __restrict__ gfeat,
    const float* __restrict__ Wg1, const float* __restrict__ bg1,
    const float* __restrict__ Wg2, const float* __restrict__ bg2,
    const float* __restrict__ Wg3, const float* __restrict__ bg3,
    const float* __restrict__ Wo1, const float* __restrict__ bo1,
    const float* __restrict__ Wo2, const float* __restrict__ bo2,
    const float* __restrict__ Wo3, const float* __restrict__ bo3,
    float* __restrict__ out) {
  __shared__ float smem[TB * 232 + TB * 128];
  float* svec  = smem;
  float* sbuf1 = smem + TB * 232;
  float* sbuf2 = smem;
  const int tid = threadIdx.x;
  const int b0  = blockIdx.x * TB;
  {
    const size_t gbase = (size_t)b0 * 216;
    for (int idx = tid; idx < TB * 216; idx += 256) {
      int b = idx / 216;
      int k = idx - b * 216;
      svec[b * 232 + k] = embeds[gbase + idx];
    }
  }
  if (tid < TB) {
    const float* gf = gfeat + (size_t)(b0 + tid) * GLOBF;
    float gin[16];
#pragma unroll
    for (int i = 0; i < 16; ++i) gin[i] = gf[i];
    float g1[8];
#pragma unroll
    for (int j = 0; j < 8; ++j) {
      float acc = bg1[j];
#pragma unroll
      for (int i = 0; i < 16; ++i) acc = fmaf(gin[i], Wg1[i * 8 + j], acc);
      g1[j] = fmaxf(acc, 0.f);
    }
    float g2[8];
#pragma unroll
    for (int j = 0; j < 8; ++j) {
      float acc = bg2[j];
#pragma unroll
      for (int i = 0; i < 8; ++i) acc = fmaf(g1[i], Wg2[i * 8 + j], acc);
      g2[j] = fmaxf(acc, 0.f);
    }
#pragma unroll
    for (int j = 0; j < 16; ++j) {
      float acc = bg3[j];
#pragma unroll
      for (int i = 0; i < 8; ++i) acc = fmaf(g2[i], Wg3[i * 16 + j], acc);
      svec[tid * 232 + 216 + j] = fmaxf(acc, 0.f);
    }
  }
  __syncthreads();
  const int c0 = (tid & 31) * 4;
  const int rb = (tid >> 5) * 4;
  {
    float acc[4][4];
#pragma unroll
    for (int r = 0; r < 4; ++r)
#pragma unroll
      for (int c = 0; c < 4; ++c) acc[r][c] = 0.f;
#pragma unroll 4
    for (int i = 0; i < 232; ++i) {
      const float4 w = *reinterpret_cast<const float4*>(Wo1 + (size_t)i * 128 + c0);
#pragma unroll
      for (int r = 0; r < 4; ++r) {
        float v = svec[(rb + r) * 232 + i];
        acc[r][0] = fmaf(v, w.x, acc[r][0]);
        acc[r][1] = fmaf(v, w.y, acc[r][1]);
        acc[r][2] = fmaf(v, w.z, acc[r][2]);
        acc[r][3] = fmaf(v, w.w, acc[r][3]);
      }
    }
    const float4 bv = *reinterpret_cast<const float4*>(bo1 + c0);
#pragma unroll
    for (int r = 0; r < 4; ++r) {
      float4 o;
      o.x = fmaxf(acc[r][0] + bv.x, 0.f);
      o.y = fmaxf(acc[r][1] + bv.y, 0.f);
      o.z = fmaxf(acc[r][2] + bv.z, 0.f);
      o.w = fmaxf(acc[r][3] + bv.w, 0.f);
      *reinterpret_cast<float4*>(sbuf1 + (rb + r) * 128 + c0) = o;
    }
  }
  __syncthreads();
  {
    float acc[4][4];
#pragma unroll
    for (int r = 0; r < 4; ++r)
#pragma unroll
      for (int c = 0; c < 4; ++c) acc[r][c] = 0.f;
#pragma unroll 4
    for (int i = 0; i < 128; ++i) {
      const float4 w = *reinterpret_cast<const float4*>(Wo2 + (size_t)i * 128 + c0);
#pragma unroll
      for (int r = 0; r < 4; ++r) {
        float v = sbuf1[(rb + r) * 128 + i];
        acc[r][0] = fmaf(v, w.x, acc[r][0]);
        acc[r][1] = fmaf(v, w.y, acc[r][1]);
        acc[r][2] = fmaf(v, w.z, acc[r][2]);
        acc[r][3] = fmaf(v, w.w, acc[r][3]);
      }
    }
    const float4 bv = *reinterpret_cast<const float4*>(bo2 + c0);
#pragma unroll
    for (int r = 0; r < 4; ++r) {
      float4 o;
      o.x = fmaxf(acc[r][0] + bv.x, 0.f);
      o.y = fmaxf(acc[r][1] + bv.y, 0.f);
      o.z = fmaxf(acc[r][2] + bv.z, 0.f);
      o.w = fmaxf(acc[r][3] + bv.w, 0.f);
      *reinterpret_cast<float4*>(sbuf2 + (rb + r) * 128 + c0) = o;
    }
  }
  __syncthreads();
  {
    const int c2 = (tid & 31) * 2;
    float acc[4][2];
#pragma unroll
    for (int r = 0; r < 4; ++r) { acc[r][0] = 0.f; acc[r][1] = 0.f; }
#pragma unroll 4
    for (int i = 0; i < 128; ++i) {
      const float2 w = *reinterpret_cast<const float2*>(Wo3 + (size_t)i * 64 + c2);
#pragma unroll
      for (int r = 0; r < 4; ++r) {
        float v = sbuf2[(rb + r) * 128 + i];
        acc[r][0] = fmaf(v, w.x, acc[r][0]);
        acc[r][1] = fmaf(v, w.y, acc[r][1]);
      }
    }
    const float2 bv = *reinterpret_cast<const float2*>(bo3 + c2);
#pragma unroll
    for (int r = 0; r < 4; ++r) {
      float2 o;
      o.x = acc[r][0] + bv.x;
      o.y = acc[r][1] + bv.y;
      *reinterpret_cast<float2*>(out + (size_t)(b0 + rb + r) * 64 + c2) = o;
    }
  }
}

// ---------------------------------------------------------------------------
extern "C" void kernel_launch(void* const* d_in, const int* in_sizes, int n_in,
                              void* d_out, int out_size, void* d_ws, size_t ws_size,
                              hipStream_t stream) {
  const float* x      = (const float*)d_in[0];
  const int*   ei     = (const int*)d_in[1];
  const float* ea     = (const float*)d_in[2];
  const float* gfeat  = (const float*)d_in[3];
  const float* W1_rel = (const float*)d_in[5];
  const float* b1     = (const float*)d_in[6];
  const float* W1_root= (const float*)d_in[7];
  const float* W2_rel = (const float*)d_in[8];
  const float* b2     = (const float*)d_in[9];
  const float* W2_root= (const float*)d_in[10];
  const float* Wg1 = (const float*)d_in[11];
  const float* bg1 = (const float*)d_in[12];
  const float* Wg2 = (const float*)d_in[13];
  const float* bg2 = (const float*)d_in[14];
  const float* Wg3 = (const float*)d_in[15];
  const float* bg3 = (const float*)d_in[16];
  const float* Wo1 = (const float*)d_in[17];
  const float* bo1 = (const float*)d_in[18];
  const float* Wo2 = (const float*)d_in[19];
  const float* bo2 = (const float*)d_in[20];
  const float* Wo3 = (const float*)d_in[21];
  const float* bo3 = (const float*)d_in[22];
  float* outp = (float*)d_out;

  // workspace (~123 MB)
  uint2*    rec    = (uint2*)d_ws;                       // NE*8B
  float*    z2     = (float*)(rec + NE);                 // NN*4 f
  float*    r2     = z2 + (size_t)NN * 4;                // NN*4 f
  float*    embeds = r2 + (size_t)NN * 4;                // NN*4 f
  unsigned* hist   = (unsigned*)(embeds + (size_t)NN * 4); // NBK
  unsigned* base   = hist + NBK;                         // NBK+1
  unsigned* cursor = base + NBK + 1;                     // NBK

  hipMemsetAsync(hist, 0, NBK * sizeof(unsigned), stream);
  k_histl<<<HB, 256, 0, stream>>>(ei, hist);
  k_scan <<<1, 1024, 0, stream>>>(hist, base, cursor);
  for (unsigned q = 0; q < 4; ++q)
    k_place<<<QE / 256, 256, 0, stream>>>(ei, ea, cursor, rec, q * QE);
  for (unsigned q = 0; q < 4; ++q)
    k_conv1s<<<QBK, 256, 0, stream>>>(rec, base, x, W1_rel, b1, W1_root,
                                      W2_rel, b2, W2_root, z2, r2, q * QBK);
  for (unsigned q = 0; q < 4; ++q)
    k_conv2s<<<QBK, 256, 0, stream>>>(rec, base, z2, r2, embeds, q * QBK);
  k_final<<<BD / TB, 256, 0, stream>>>(embeds, gfeat,
                                       Wg1, bg1, Wg2, bg2, Wg3, bg3,
                                       Wo1, bo1, Wo2, bo2, Wo3, bo3, outp);
}